// Round 2
// baseline (634.540 us; speedup 1.0000x reference)
//
#include <hip/hip_runtime.h>
#include <cstdint>
#include <cstddef>

#define SEQ     2048
#define NBATCH  2
#define BL      (NBATCH*SEQ)     // 4096
#define DMODEL  2048
#define DINNER  4096
#define DSTATE  128
#define HEADDIM 64
#define NHEADS  64
#define DXBC    4352
#define DPROJ   8512
#define NPAD    8576             // padded D_IN_PROJ (67*128)
#define NCHUNK  16
#define CHUNKL  128

typedef __bf16 bf16x8_t __attribute__((ext_vector_type(8)));
typedef float f32x4_t __attribute__((ext_vector_type(4)));
typedef unsigned short u16x8_t __attribute__((ext_vector_type(8)));
typedef unsigned short u16x4_t __attribute__((ext_vector_type(4)));
typedef __attribute__((address_space(1))) unsigned int as1_u32;
typedef __attribute__((address_space(3))) unsigned int as3_u32;

__device__ __forceinline__ unsigned short f2bf(float f) {
  unsigned u = __builtin_bit_cast(unsigned, f);
  u += 0x7FFFu + ((u >> 16) & 1u);
  return (unsigned short)(u >> 16);
}
__device__ __forceinline__ float bf2f(unsigned short h) {
  unsigned u = ((unsigned)h) << 16;
  return __builtin_bit_cast(float, u);
}
__device__ __forceinline__ void gload16(const void* g, void* l) {
  __builtin_amdgcn_global_load_lds((const as1_u32*)g, (as3_u32*)l, 16, 0, 0);
}
__device__ __forceinline__ f32x4_t mfma16(u16x8_t a, u16x8_t b, f32x4_t c) {
  return __builtin_amdgcn_mfma_f32_16x16x32_bf16(
      __builtin_bit_cast(bf16x8_t, a), __builtin_bit_cast(bf16x8_t, b), c, 0, 0, 0);
}
__device__ __forceinline__ float siluf(float x) { return x / (1.f + __expf(-x)); }

// ---------------- converts ----------------
__global__ __launch_bounds__(256) void cvt_kernel(const float* __restrict__ src,
                                                  unsigned short* __restrict__ dst, int n) {
  int idx = (blockIdx.x * 256 + threadIdx.x) * 4;
  if (idx >= n) return;
  float4 v = *(const float4*)&src[idx];
  u16x4_t o; o[0] = f2bf(v.x); o[1] = f2bf(v.y); o[2] = f2bf(v.z); o[3] = f2bf(v.w);
  *(u16x4_t*)&dst[idx] = o;
}

__global__ __launch_bounds__(256) void cvt_win_kernel(const float* __restrict__ W,
                                                      unsigned short* __restrict__ dst) {
  int idx = (blockIdx.x * 256 + threadIdx.x) * 4;
  if (idx >= NPAD * DMODEL) return;
  int e = idx / DMODEL;
  u16x4_t o;
  if (e < DPROJ) {
    float4 v = *(const float4*)&W[idx];
    o[0] = f2bf(v.x); o[1] = f2bf(v.y); o[2] = f2bf(v.z); o[3] = f2bf(v.w);
  } else {
    o[0] = 0; o[1] = 0; o[2] = 0; o[3] = 0;
  }
  *(u16x4_t*)&dst[idx] = o;
}

// ---------------- GEMM: C[M][N] = A[M][K] * B[N][K]^T (bf16 in) ------
// BM=BN=128, BK=64, 256 threads (4 waves, 2x2), 4x4 16x16x32 frags per wave.
template <bool BF16OUT>
__global__ __launch_bounds__(256) void gemm_bt_kernel(const unsigned short* __restrict__ A,
                                                      const unsigned short* __restrict__ B,
                                                      void* __restrict__ Cp,
                                                      int M, int N, int K) {
  __shared__ unsigned short As[128 * 64];
  __shared__ unsigned short Bs[128 * 64];
  const int n0 = blockIdx.x * 128;
  const int m0 = blockIdx.y * 128;
  const int t = threadIdx.x, lane = t & 63, w = t >> 6;
  const int wr = w >> 1, wc = w & 1;
  const int srow = t >> 3;           // 0..31
  const int scol = (t & 7) * 8;      // 8 bf16 = 16B
  f32x4_t acc[4][4];
#pragma unroll
  for (int i = 0; i < 4; ++i)
#pragma unroll
    for (int j = 0; j < 4; ++j) acc[i][j] = (f32x4_t){0.f, 0.f, 0.f, 0.f};

  const int nk = K >> 6;
  for (int kt = 0; kt < nk; ++kt) {
    const int k0 = kt << 6;
#pragma unroll
    for (int s = 0; s < 4; ++s) {
      int r = s * 32 + srow;
      gload16(&A[(size_t)(m0 + r) * K + k0 + scol], &As[r * 64 + scol]);
      gload16(&B[(size_t)(n0 + r) * K + k0 + scol], &Bs[r * 64 + scol]);
    }
    __syncthreads();
#pragma unroll
    for (int ks = 0; ks < 2; ++ks) {
      const int kk = ks * 32 + (lane >> 4) * 8;
      u16x8_t af[4], bfr[4];
#pragma unroll
      for (int i = 0; i < 4; ++i) {
        af[i]  = *(const u16x8_t*)&As[(wr * 64 + i * 16 + (lane & 15)) * 64 + kk];
        bfr[i] = *(const u16x8_t*)&Bs[(wc * 64 + i * 16 + (lane & 15)) * 64 + kk];
      }
#pragma unroll
      for (int i = 0; i < 4; ++i)
#pragma unroll
        for (int j = 0; j < 4; ++j) acc[i][j] = mfma16(af[i], bfr[j], acc[i][j]);
    }
    __syncthreads();
  }
#pragma unroll
  for (int i = 0; i < 4; ++i) {
    const int mbase = m0 + wr * 64 + i * 16 + (lane >> 4) * 4;
#pragma unroll
    for (int j = 0; j < 4; ++j) {
      const int n = n0 + wc * 64 + j * 16 + (lane & 15);
#pragma unroll
      for (int r = 0; r < 4; ++r) {
        if (BF16OUT) ((unsigned short*)Cp)[(size_t)(mbase + r) * N + n] = f2bf(acc[i][j][r]);
        else         ((float*)Cp)[(size_t)(mbase + r) * N + n] = acc[i][j][r];
      }
    }
  }
}

// ---------------- depthwise causal conv + silu (bf16 in/out) ----------------
__global__ __launch_bounds__(256) void conv_kernel(const unsigned short* __restrict__ zx,
                                                   const float* __restrict__ conv_w,
                                                   const float* __restrict__ conv_b,
                                                   unsigned short* __restrict__ xc) {
  long long idx = (long long)blockIdx.x * 256 + threadIdx.x;
  if (idx >= (long long)BL * DXBC) return;
  int e = (int)(idx % DXBC);
  int bl = (int)(idx / DXBC);
  int l = bl % SEQ, b = bl / SEQ;
  float acc = conv_b[e];
#pragma unroll
  for (int wi = 0; wi < 4; ++wi) {
    int ll = l - 3 + wi;
    if (ll >= 0) acc += bf2f(zx[((size_t)b * SEQ + ll) * NPAD + DINNER + e]) * conv_w[e * 4 + wi];
  }
  xc[(size_t)bl * DXBC + e] = f2bf(siluf(acc));
}

// ---------------- dt softplus + per-chunk cumsum of dA ----------------
__global__ __launch_bounds__(128) void dt_kernel(const unsigned short* __restrict__ zx,
                                                 const float* __restrict__ dt_bias,
                                                 const float* __restrict__ A_log,
                                                 float* __restrict__ dt_soft,   // [b][h][l]
                                                 float* __restrict__ Acs,       // [b][h][c][128]
                                                 float* __restrict__ cdecay) {  // [b][h][c]
  int blk = blockIdx.x;                       // (b*64+h)*16+c
  int c = blk & 15, h = (blk >> 4) & 63, b = blk >> 10;
  int i = threadIdx.x;
  int l = c * CHUNKL + i;
  float raw = bf2f(zx[((size_t)b * SEQ + l) * NPAD + (DINNER + DXBC) + h]) + dt_bias[h];
  float dt = (raw > 20.f) ? raw : log1pf(__expf(raw));
  dt_soft[((size_t)b * 64 + h) * SEQ + l] = dt;
  float A = -__expf(A_log[h]);
  __shared__ float sbuf[128];
  sbuf[i] = dt * A;
  __syncthreads();
  for (int ofs = 1; ofs < 128; ofs <<= 1) {
    float v = (i >= ofs) ? sbuf[i - ofs] : 0.f;
    __syncthreads();
    sbuf[i] += v;
    __syncthreads();
  }
  float cs = sbuf[i];
  Acs[(((size_t)b * 64 + h) * 16 + c) * 128 + i] = cs;
  if (i == 127) cdecay[((size_t)b * 64 + h) * 16 + c] = __expf(cs);
}

// ---------------- xdt^T builder: xdtT[b][h][p][l] = x[b,l,h*64+p]*dt ----------
__global__ __launch_bounds__(256) void xdt_kernel(const unsigned short* __restrict__ xc,
                                                  const float* __restrict__ dt_soft,
                                                  unsigned short* __restrict__ xdtT) {
  int blk = blockIdx.x;                       // (b*64+h)*16+lt
  int lt = blk & 15, h = (blk >> 4) & 63, b = blk >> 10;
  __shared__ unsigned short tile[128][66];
  __shared__ float dts[128];
  int t = threadIdx.x;
  const unsigned short* xg = xc + ((size_t)b * SEQ + lt * 128) * DXBC + h * 64;
#pragma unroll
  for (int k = 0; k < 32; ++k) {
    int idx = t + k * 256;
    int row = idx >> 6, col = idx & 63;
    tile[row][col] = xg[(size_t)row * DXBC + col];
  }
  if (t < 128) dts[t] = dt_soft[((size_t)b * 64 + h) * SEQ + lt * 128 + t];
  __syncthreads();
  unsigned short* xo = xdtT + (((size_t)b * 64 + h) * 64) * SEQ + lt * 128;
#pragma unroll
  for (int k = 0; k < 32; ++k) {
    int idx = t + k * 256;
    int p = idx >> 7, j = idx & 127;
    xo[(size_t)p * SEQ + j] = f2bf(bf2f(tile[j][p]) * dts[j]);
  }
}

// ---------------- B transpose from xc: BT[b][n][l] ----------------
__global__ __launch_bounds__(256) void btr_kernel(const unsigned short* __restrict__ xc,
                                                  unsigned short* __restrict__ BT) {
  int blk = blockIdx.x;                       // b*16+lt
  int lt = blk & 15, b = blk >> 4;
  __shared__ unsigned short tile[128][129];
  int t = threadIdx.x;
  const unsigned short* src = xc + ((size_t)b * SEQ + lt * 128) * DXBC + DINNER;
#pragma unroll
  for (int k = 0; k < 64; ++k) {
    int idx = t + k * 256;
    int j = idx >> 7, n = idx & 127;
    tile[j][n] = src[(size_t)j * DXBC + n];
  }
  __syncthreads();
  unsigned short* dst = BT + (size_t)b * 128 * SEQ + lt * 128;
#pragma unroll
  for (int k = 0; k < 64; ++k) {
    int idx = t + k * 256;
    int n = idx >> 7, j = idx & 127;
    dst[(size_t)n * SEQ + j] = tile[j][n];
  }
}

// ---------------- SSD per-chunk states: states[b][c][h][p][n] ----------------
__global__ __launch_bounds__(256) void ssd_states_kernel(const unsigned short* __restrict__ BT,
                                                         const unsigned short* __restrict__ xdtT,
                                                         const float* __restrict__ Acs,
                                                         float* __restrict__ states) {
  int blk = blockIdx.x;                       // ((b*16+c)*64+h)
  int h = blk & 63, c = (blk >> 6) & 15, b = blk >> 10;
  __shared__ unsigned short BTs[128 * 128];   // [n][j]
  __shared__ unsigned short xs[64 * 128];     // [p][j]
  __shared__ float dec[128];
  int t = threadIdx.x, lane = t & 63, w = t >> 6, wr = w >> 1, wc = w & 1;
  int srow = t >> 4, scol = (t & 15) * 8;
  const unsigned short* BTb = BT + (size_t)b * 128 * SEQ + c * 128;
#pragma unroll
  for (int s = 0; s < 8; ++s) {
    int r = s * 16 + srow;
    gload16(&BTb[(size_t)r * SEQ + scol], &BTs[r * 128 + scol]);
  }
  const unsigned short* xb = xdtT + (((size_t)b * 64 + h) * 64) * SEQ + c * 128;
#pragma unroll
  for (int s = 0; s < 4; ++s) {
    int r = s * 16 + srow;
    gload16(&xb[(size_t)r * SEQ + scol], &xs[r * 128 + scol]);
  }
  const float* acsr = Acs + (((size_t)b * 64 + h) * 16 + c) * 128;
  float alast = acsr[127];
  if (t < 128) dec[t] = __expf(alast - acsr[t]);
  __syncthreads();

  f32x4_t acc[2][4];
#pragma unroll
  for (int i = 0; i < 2; ++i)
#pragma unroll
    for (int j = 0; j < 4; ++j) acc[i][j] = (f32x4_t){0.f, 0.f, 0.f, 0.f};
#pragma unroll
  for (int ks = 0; ks < 4; ++ks) {
    const int kk = ks * 32 + (lane >> 4) * 8;
    float d8[8];
#pragma unroll
    for (int e = 0; e < 8; ++e) d8[e] = dec[kk + e];
    u16x8_t af[2], bfr[4];
#pragma unroll
    for (int i = 0; i < 2; ++i) {
      u16x8_t raw = *(const u16x8_t*)&xs[(wr * 32 + i * 16 + (lane & 15)) * 128 + kk];
      u16x8_t sc;
#pragma unroll
      for (int e = 0; e < 8; ++e) sc[e] = f2bf(bf2f(raw[e]) * d8[e]);
      af[i] = sc;
    }
#pragma unroll
    for (int j = 0; j < 4; ++j)
      bfr[j] = *(const u16x8_t*)&BTs[(wc * 64 + j * 16 + (lane & 15)) * 128 + kk];
#pragma unroll
    for (int i = 0; i < 2; ++i)
#pragma unroll
      for (int j = 0; j < 4; ++j) acc[i][j] = mfma16(af[i], bfr[j], acc[i][j]);
  }
  float* so = states + ((((size_t)b * 16 + c) * 64 + h) * 64) * 128;
#pragma unroll
  for (int i = 0; i < 2; ++i) {
    int pbase = wr * 32 + i * 16 + (lane >> 4) * 4;
#pragma unroll
    for (int j = 0; j < 4; ++j) {
      int n = wc * 64 + j * 16 + (lane & 15);
#pragma unroll
      for (int r = 0; r < 4; ++r) so[(size_t)(pbase + r) * 128 + n] = acc[i][j][r];
    }
  }
}

// ---------------- inter-chunk scan ----------------
__global__ __launch_bounds__(256) void ssd_scan_kernel(const float* __restrict__ states,
                                                       const float* __restrict__ cdecay,
                                                       unsigned short* __restrict__ prevb) {
  int blk = blockIdx.x;                       // b*64+h
  int h = blk & 63, b = blk >> 6;
  int t = threadIdx.x;
  float carry[32];
#pragma unroll
  for (int k = 0; k < 32; ++k) carry[k] = 0.f;
  const float* cd = cdecay + ((size_t)b * 64 + h) * 16;
  for (int c = 0; c < 16; ++c) {
    const float* sp = states + ((((size_t)b * 16 + c) * 64 + h) * 64) * 128;
    unsigned short* pp = prevb + ((((size_t)b * 16 + c) * 64 + h) * 64) * 128;
    float d = cd[c];
#pragma unroll
    for (int k = 0; k < 32; ++k) {
      int idx = t + k * 256;
      pp[idx] = f2bf(carry[k]);
      carry[k] = carry[k] * d + sp[idx];
    }
  }
}

// ---------------- SSD Y = Y_diag + Y_off + D*x ----------------
__global__ __launch_bounds__(256) void ssd_y_kernel(const unsigned short* __restrict__ xc,
                                                    const unsigned short* __restrict__ xdtT,
                                                    const unsigned short* __restrict__ prevb,
                                                    const float* __restrict__ Acs,
                                                    const float* __restrict__ Dp,
                                                    float* __restrict__ Y) {
  int blk = blockIdx.x;                       // ((b*16+c)*64+h)
  int h = blk & 63, c = (blk >> 6) & 15, b = blk >> 10;
  __shared__ unsigned short Bs[128 * 128];    // [j][n], reused as M[i][j]
  __shared__ unsigned short Cs[128 * 128];    // [i][n]
  __shared__ unsigned short xs[64 * 128];     // [p][j]
  __shared__ unsigned short ps[64 * 128];     // [p][n]
  __shared__ float acs_s[128];
  int t = threadIdx.x, lane = t & 63, w = t >> 6, wr = w >> 1, wc = w & 1;
  int srow = t >> 4, scol = (t & 15) * 8;
  const unsigned short* Bg = xc + ((size_t)b * SEQ + c * 128) * DXBC + DINNER;
  const unsigned short* Cg = Bg + DSTATE;
#pragma unroll
  for (int s = 0; s < 8; ++s) {
    int r = s * 16 + srow;
    gload16(&Bg[(size_t)r * DXBC + scol], &Bs[r * 128 + scol]);
    gload16(&Cg[(size_t)r * DXBC + scol], &Cs[r * 128 + scol]);
  }
  const unsigned short* xg = xdtT + (((size_t)b * 64 + h) * 64) * SEQ + c * 128;
#pragma unroll
  for (int s = 0; s < 4; ++s) {
    int r = s * 16 + srow;
    gload16(&xg[(size_t)r * SEQ + scol], &xs[r * 128 + scol]);
  }
  const unsigned short* pg = prevb + ((((size_t)b * 16 + c) * 64 + h) * 64) * 128;
#pragma unroll
  for (int s = 0; s < 4; ++s) {
    int r = s * 16 + srow;
    gload16(&pg[r * 128 + scol], &ps[r * 128 + scol]);
  }
  const float* acsr = Acs + (((size_t)b * 64 + h) * 16 + c) * 128;
  if (t < 128) acs_s[t] = acsr[t];
  __syncthreads();

  // 1) CB^T: cbt[.][.] -> D[m=j][n=i] = sum_n B[j,n] C[i,n]
  f32x4_t cbt[4][4];
#pragma unroll
  for (int i = 0; i < 4; ++i)
#pragma unroll
    for (int j = 0; j < 4; ++j) cbt[i][j] = (f32x4_t){0.f, 0.f, 0.f, 0.f};
#pragma unroll
  for (int ks = 0; ks < 4; ++ks) {
    const int kk = ks * 32 + (lane >> 4) * 8;
    u16x8_t af[4], bfr[4];
#pragma unroll
    for (int i = 0; i < 4; ++i) {
      af[i]  = *(const u16x8_t*)&Bs[(wr * 64 + i * 16 + (lane & 15)) * 128 + kk];
      bfr[i] = *(const u16x8_t*)&Cs[(wc * 64 + i * 16 + (lane & 15)) * 128 + kk];
    }
#pragma unroll
    for (int i = 0; i < 4; ++i)
#pragma unroll
      for (int j = 0; j < 4; ++j) cbt[i][j] = mfma16(af[i], bfr[j], cbt[i][j]);
  }
  __syncthreads();   // all waves done reading Bs before M overwrites it
  // build M[i][j] = (i>=j) ? CB * exp(acs[i]-acs[j]) : 0   (stored into Bs)
#pragma unroll
  for (int fi = 0; fi < 4; ++fi) {
#pragma unroll
    for (int fj = 0; fj < 4; ++fj) {
      int i = wc * 64 + fj * 16 + (lane & 15);
      int jb = wr * 64 + fi * 16 + (lane >> 4) * 4;
      float ai = acs_s[i];
      u16x4_t m4;
#pragma unroll
      for (int r = 0; r < 4; ++r) {
        int j = jb + r;
        float v = (i >= j) ? cbt[fi][fj][r] * __expf(ai - acs_s[j]) : 0.f;
        m4[r] = f2bf(v);
      }
      *(u16x4_t*)&Bs[i * 128 + jb] = m4;
    }
  }
  __syncthreads();

  // 2) Y_diag[i][p] = sum_j M[i,j] xdtT[p,j] ; 3) Y_off[i][p] = sum_n C[i,n] prev[p,n]
  f32x4_t accY[4][2], accO[4][2];
#pragma unroll
  for (int i = 0; i < 4; ++i)
#pragma unroll
    for (int j = 0; j < 2; ++j) {
      accY[i][j] = (f32x4_t){0.f, 0.f, 0.f, 0.f};
      accO[i][j] = (f32x4_t){0.f, 0.f, 0.f, 0.f};
    }
#pragma unroll
  for (int ks = 0; ks < 4; ++ks) {
    const int kk = ks * 32 + (lane >> 4) * 8;
    u16x8_t af[4], bfr[2], cf[4], pf[2];
#pragma unroll
    for (int i = 0; i < 4; ++i) {
      af[i] = *(const u16x8_t*)&Bs[(wr * 64 + i * 16 + (lane & 15)) * 128 + kk];
      cf[i] = *(const u16x8_t*)&Cs[(wr * 64 + i * 16 + (lane & 15)) * 128 + kk];
    }
#pragma unroll
    for (int j = 0; j < 2; ++j) {
      bfr[j] = *(const u16x8_t*)&xs[(wc * 32 + j * 16 + (lane & 15)) * 128 + kk];
      pf[j]  = *(const u16x8_t*)&ps[(wc * 32 + j * 16 + (lane & 15)) * 128 + kk];
    }
#pragma unroll
    for (int i = 0; i < 4; ++i)
#pragma unroll
      for (int j = 0; j < 2; ++j) {
        accY[i][j] = mfma16(af[i], bfr[j], accY[i][j]);
        accO[i][j] = mfma16(cf[i], pf[j], accO[i][j]);
      }
  }
  // epilogue
  float Dh = Dp[h];
  float* Yo = Y + ((size_t)b * SEQ + c * 128) * DINNER + h * 64;
  const unsigned short* xo = xc + ((size_t)b * SEQ + c * 128) * DXBC + h * 64;
#pragma unroll
  for (int fi = 0; fi < 4; ++fi) {
    int ibase = wr * 64 + fi * 16 + (lane >> 4) * 4;
#pragma unroll
    for (int r = 0; r < 4; ++r) {
      int i = ibase + r;
      float esc = __expf(acs_s[i]);
#pragma unroll
      for (int fj = 0; fj < 2; ++fj) {
        int p = wc * 32 + fj * 16 + (lane & 15);
        float v = accY[fi][fj][r] + accO[fi][fj][r] * esc + bf2f(xo[(size_t)i * DXBC + p]) * Dh;
        Yo[(size_t)i * DINNER + p] = v;
      }
    }
  }
}

// ---------------- gated RMSNorm -> bf16 ----------------
__global__ __launch_bounds__(256) void norm_kernel(const float* __restrict__ Y,
                                                   const unsigned short* __restrict__ zx,
                                                   const float* __restrict__ nw,
                                                   unsigned short* __restrict__ yn) {
  int bl = blockIdx.x;
  const float* yr = Y + (size_t)bl * DINNER;
  const unsigned short* zr = zx + (size_t)bl * NPAD;
  int t = threadIdx.x;
  float vals[16];
  float ss = 0.f;
#pragma unroll
  for (int k = 0; k < 16; ++k) {
    int d = t + k * 256;
    float g = yr[d] * siluf(bf2f(zr[d]));
    vals[k] = g;
    ss += g * g;
  }
#pragma unroll
  for (int o = 32; o > 0; o >>= 1) ss += __shfl_down(ss, o, 64);
  __shared__ float red[4];
  if ((t & 63) == 0) red[t >> 6] = ss;
  __syncthreads();
  float tot = red[0] + red[1] + red[2] + red[3];
  float rs = rsqrtf(tot * (1.f / (float)DINNER) + 1e-5f);
#pragma unroll
  for (int k = 0; k < 16; ++k) {
    int d = t + k * 256;
    yn[(size_t)bl * DINNER + d] = f2bf(vals[k] * rs * nw[d]);
  }
}

// ---------------- host ----------------
extern "C" void kernel_launch(void* const* d_in, const int* in_sizes, int n_in,
                              void* d_out, int out_size, void* d_ws, size_t ws_size,
                              hipStream_t stream) {
  const float* u       = (const float*)d_in[0];
  const float* W_in    = (const float*)d_in[1];
  const float* conv_w  = (const float*)d_in[2];
  const float* conv_b  = (const float*)d_in[3];
  const float* dt_bias = (const float*)d_in[4];
  const float* A_log   = (const float*)d_in[5];
  const float* Dv      = (const float*)d_in[6];
  const float* norm_w  = (const float*)d_in[7];
  const float* W_out   = (const float*)d_in[8];
  float* out = (float*)d_out;
  (void)in_sizes; (void)n_in; (void)out_size;

  // ---- byte sizes ----
  const size_t SZ_UBF    = (size_t)BL * DMODEL * 2;          // 16,777,216
  const size_t SZ_WIN    = (size_t)NPAD * DMODEL * 2;        // 35,127,296
  const size_t SZ_WOUT   = (size_t)DMODEL * DINNER * 2;      // 16,777,216
  const size_t SZ_XDTT   = (size_t)NBATCH * NHEADS * HEADDIM * SEQ * 2;  // 33,554,432
  const size_t SZ_ZX     = (size_t)BL * NPAD * 2;            // 70,254,592
  const size_t SZ_XC     = (size_t)BL * DXBC * 2;            // 35,651,584
  const size_t SZ_BT     = (size_t)NBATCH * DSTATE * SEQ * 2;            // 1,048,576
  const size_t SZ_DTS    = (size_t)NBATCH * NHEADS * SEQ * 4;            // 1,048,576
  const size_t SZ_ACS    = (size_t)NBATCH * NHEADS * NCHUNK * 128 * 4;   // 1,048,576
  const size_t SZ_CDEC   = (size_t)NBATCH * NHEADS * NCHUNK * 4;         // 8,192
  const size_t SZ_STATES = (size_t)NBATCH * NCHUNK * NHEADS * HEADDIM * DSTATE * 4; // 67,108,864 (== Yb f32)
  const size_t SZ_PREV   = (size_t)NBATCH * NCHUNK * NHEADS * HEADDIM * DSTATE * 2; // 33,554,432 (== yn bf16)
  const size_t REGION_A  = SZ_UBF + SZ_WIN;                  // 51,904,512 (>= SZ_XDTT + SZ_WOUT)

  char* ws = (char*)d_ws;
  size_t off = 0;
  auto alloc = [&](size_t bytes) { char* p = ws + off; off += (bytes + 255) & ~(size_t)255; return p; };

  char* regionA = alloc(REGION_A);
  unsigned short* zx     = (unsigned short*)alloc(SZ_ZX);
  unsigned short* xc     = (unsigned short*)alloc(SZ_XC);
  unsigned short* BT     = (unsigned short*)alloc(SZ_BT);
  float* dt_soft         = (float*)alloc(SZ_DTS);
  float* Acs             = (float*)alloc(SZ_ACS);
  float* cdecay          = (float*)alloc(SZ_CDEC);
  char* statesYb         = alloc(SZ_STATES);
  char* prevYn           = alloc(SZ_PREV);
  if (off > ws_size) return;   // insufficient workspace: bail cleanly (absmax-fail, not fault)

  // regionA overlays: phase 1 (u_bf, win_bf) -> phase 2 (xdtT, wout_bf)
  unsigned short* u_bf    = (unsigned short*)regionA;
  unsigned short* win_bf  = (unsigned short*)(regionA + SZ_UBF);
  unsigned short* xdtT    = (unsigned short*)regionA;
  unsigned short* wout_bf = (unsigned short*)(regionA + SZ_XDTT);
  float* states           = (float*)statesYb;
  float* Yb               = (float*)statesYb;
  unsigned short* prevb   = (unsigned short*)prevYn;
  unsigned short* yn      = (unsigned short*)prevYn;

  // phase 1 converts
  cvt_kernel<<<dim3((BL * DMODEL / 4 + 255) / 256), dim3(256), 0, stream>>>(u, u_bf, BL * DMODEL);
  cvt_win_kernel<<<dim3(NPAD * DMODEL / 4 / 256), dim3(256), 0, stream>>>(W_in, win_bf);

  // GEMM1: zx[BL][NPAD](bf16) = u_bf[BL][DMODEL] @ win_bf[NPAD][DMODEL]^T
  gemm_bt_kernel<true><<<dim3(NPAD / 128, BL / 128), dim3(256), 0, stream>>>(u_bf, win_bf, zx, BL, NPAD, DMODEL);

  // regionA now reusable: W_out convert
  cvt_kernel<<<dim3((DMODEL * DINNER / 4 + 255) / 256), dim3(256), 0, stream>>>(W_out, wout_bf, DMODEL * DINNER);

  // conv + silu (x, B, C all inside xc)
  conv_kernel<<<dim3((int)(((size_t)BL * DXBC + 255) / 256)), dim3(256), 0, stream>>>(zx, conv_w, conv_b, xc);

  // dt softplus + cumsum
  dt_kernel<<<dim3(NBATCH * NHEADS * NCHUNK), dim3(128), 0, stream>>>(zx, dt_bias, A_log, dt_soft, Acs, cdecay);

  // xdt^T and B^T
  xdt_kernel<<<dim3(NBATCH * NHEADS * NCHUNK), dim3(256), 0, stream>>>(xc, dt_soft, xdtT);
  btr_kernel<<<dim3(NBATCH * (SEQ / 128)), dim3(256), 0, stream>>>(xc, BT);

  // SSD
  ssd_states_kernel<<<dim3(NBATCH * NCHUNK * NHEADS), dim3(256), 0, stream>>>(BT, xdtT, Acs, states);
  ssd_scan_kernel<<<dim3(NBATCH * NHEADS), dim3(256), 0, stream>>>(states, cdecay, prevb);
  ssd_y_kernel<<<dim3(NBATCH * NCHUNK * NHEADS), dim3(256), 0, stream>>>(xc, xdtT, prevb, Acs, Dv, Yb);

  // gated RMSNorm (Yb -> yn; yn aliases prevb which is dead now)
  norm_kernel<<<dim3(BL), dim3(256), 0, stream>>>(Yb, zx, norm_w, yn);

  // GEMM2: out[BL][DMODEL](f32) = yn[BL][DINNER] @ wout_bf[DMODEL][DINNER]^T
  gemm_bt_kernel<false><<<dim3(DMODEL / 128, BL / 128), dim3(256), 0, stream>>>(yn, wout_bf, out, BL, DMODEL, DINNER);
}

// Round 3
// 628.594 us; speedup vs baseline: 1.0095x; 1.0095x over previous
//
#include <hip/hip_runtime.h>
#include <cstdint>
#include <cstddef>

#define SEQ     2048
#define NBATCH  2
#define BL      (NBATCH*SEQ)     // 4096
#define DMODEL  2048
#define DINNER  4096
#define DSTATE  128
#define HEADDIM 64
#define NHEADS  64
#define DXBC    4352
#define DPROJ   8512
#define NPAD    8576             // padded D_IN_PROJ (67*128)
#define NCHUNK  16
#define CHUNKL  128

typedef __bf16 bf16x8_t __attribute__((ext_vector_type(8)));
typedef float f32x4_t __attribute__((ext_vector_type(4)));
typedef unsigned short u16x8_t __attribute__((ext_vector_type(8)));
typedef unsigned short u16x4_t __attribute__((ext_vector_type(4)));
typedef __attribute__((address_space(1))) unsigned int as1_u32;
typedef __attribute__((address_space(3))) unsigned int as3_u32;

__device__ __forceinline__ unsigned short f2bf(float f) {
  unsigned u = __builtin_bit_cast(unsigned, f);
  u += 0x7FFFu + ((u >> 16) & 1u);
  return (unsigned short)(u >> 16);
}
__device__ __forceinline__ float bf2f(unsigned short h) {
  unsigned u = ((unsigned)h) << 16;
  return __builtin_bit_cast(float, u);
}
__device__ __forceinline__ void gload16(const void* g, void* l) {
  __builtin_amdgcn_global_load_lds((const as1_u32*)g, (as3_u32*)l, 16, 0, 0);
}
__device__ __forceinline__ f32x4_t mfma16(u16x8_t a, u16x8_t b, f32x4_t c) {
  return __builtin_amdgcn_mfma_f32_16x16x32_bf16(
      __builtin_bit_cast(bf16x8_t, a), __builtin_bit_cast(bf16x8_t, b), c, 0, 0, 0);
}
__device__ __forceinline__ float siluf(float x) { return x / (1.f + __expf(-x)); }

// ---------------- converts ----------------
__global__ __launch_bounds__(256) void cvt_kernel(const float* __restrict__ src,
                                                  unsigned short* __restrict__ dst, int n) {
  int idx = (blockIdx.x * 256 + threadIdx.x) * 4;
  if (idx >= n) return;
  float4 v = *(const float4*)&src[idx];
  u16x4_t o; o[0] = f2bf(v.x); o[1] = f2bf(v.y); o[2] = f2bf(v.z); o[3] = f2bf(v.w);
  *(u16x4_t*)&dst[idx] = o;
}

__global__ __launch_bounds__(256) void cvt_win_kernel(const float* __restrict__ W,
                                                      unsigned short* __restrict__ dst) {
  int idx = (blockIdx.x * 256 + threadIdx.x) * 4;
  if (idx >= NPAD * DMODEL) return;
  int e = idx / DMODEL;
  u16x4_t o;
  if (e < DPROJ) {
    float4 v = *(const float4*)&W[idx];
    o[0] = f2bf(v.x); o[1] = f2bf(v.y); o[2] = f2bf(v.z); o[3] = f2bf(v.w);
  } else {
    o[0] = 0; o[1] = 0; o[2] = 0; o[3] = 0;
  }
  *(u16x4_t*)&dst[idx] = o;
}

// ---------------- GEMM: C[M][N] = A[M][K] * B[N][K]^T (bf16 in) ------
// 1-D grid, bijective XCD-chunk swizzle + 4-row-band column-major traversal:
// each XCD owns a contiguous band of 4 M-rows swept column-major, so 4 A-panels
// (2 MB) stay L2-resident and each B-panel (0.5 MB) is used 4x back-to-back.
// Requires nwg%8==0 and (M/128)%4==0 (both GEMMs: gy=32).
template <bool BF16OUT>
__global__ __launch_bounds__(256) void gemm_bt_kernel(const unsigned short* __restrict__ A,
                                                      const unsigned short* __restrict__ B,
                                                      void* __restrict__ Cp,
                                                      int M, int N, int K, int gx) {
  __shared__ unsigned short As[128 * 64];
  __shared__ unsigned short Bs[128 * 64];
  const int nwg = gridDim.x;
  const int q = nwg >> 3;                       // blocks per XCD chunk
  const int l = blockIdx.x;
  const int newid = (l & 7) * q + (l >> 3);     // bijective chunking
  const int band = newid / (gx * 4);
  const int idx  = newid % (gx * 4);
  const int bn = idx >> 2;
  const int bm = band * 4 + (idx & 3);
  const int n0 = bn * 128;
  const int m0 = bm * 128;
  const int t = threadIdx.x, lane = t & 63, w = t >> 6;
  const int wr = w >> 1, wc = w & 1;
  const int srow = t >> 3;           // 0..31
  const int scol = (t & 7) * 8;      // 8 bf16 = 16B
  f32x4_t acc[4][4];
#pragma unroll
  for (int i = 0; i < 4; ++i)
#pragma unroll
    for (int j = 0; j < 4; ++j) acc[i][j] = (f32x4_t){0.f, 0.f, 0.f, 0.f};

  const int nk = K >> 6;
  for (int kt = 0; kt < nk; ++kt) {
    const int k0 = kt << 6;
#pragma unroll
    for (int s = 0; s < 4; ++s) {
      int r = s * 32 + srow;
      gload16(&A[(size_t)(m0 + r) * K + k0 + scol], &As[r * 64 + scol]);
      gload16(&B[(size_t)(n0 + r) * K + k0 + scol], &Bs[r * 64 + scol]);
    }
    __syncthreads();
#pragma unroll
    for (int ks = 0; ks < 2; ++ks) {
      const int kk = ks * 32 + (lane >> 4) * 8;
      u16x8_t af[4], bfr[4];
#pragma unroll
      for (int i = 0; i < 4; ++i) {
        af[i]  = *(const u16x8_t*)&As[(wr * 64 + i * 16 + (lane & 15)) * 64 + kk];
        bfr[i] = *(const u16x8_t*)&Bs[(wc * 64 + i * 16 + (lane & 15)) * 64 + kk];
      }
#pragma unroll
      for (int i = 0; i < 4; ++i)
#pragma unroll
        for (int j = 0; j < 4; ++j) acc[i][j] = mfma16(af[i], bfr[j], acc[i][j]);
    }
    __syncthreads();
  }
#pragma unroll
  for (int i = 0; i < 4; ++i) {
    const int mbase = m0 + wr * 64 + i * 16 + (lane >> 4) * 4;
#pragma unroll
    for (int j = 0; j < 4; ++j) {
      const int n = n0 + wc * 64 + j * 16 + (lane & 15);
#pragma unroll
      for (int r = 0; r < 4; ++r) {
        if (BF16OUT) ((unsigned short*)Cp)[(size_t)(mbase + r) * N + n] = f2bf(acc[i][j][r]);
        else         ((float*)Cp)[(size_t)(mbase + r) * N + n] = acc[i][j][r];
      }
    }
  }
}

// ---------------- depthwise causal conv + silu (bf16 in/out) ----------------
__global__ __launch_bounds__(256) void conv_kernel(const unsigned short* __restrict__ zx,
                                                   const float* __restrict__ conv_w,
                                                   const float* __restrict__ conv_b,
                                                   unsigned short* __restrict__ xc) {
  long long idx = (long long)blockIdx.x * 256 + threadIdx.x;
  if (idx >= (long long)BL * DXBC) return;
  int e = (int)(idx % DXBC);
  int bl = (int)(idx / DXBC);
  int l = bl % SEQ, b = bl / SEQ;
  float acc = conv_b[e];
#pragma unroll
  for (int wi = 0; wi < 4; ++wi) {
    int ll = l - 3 + wi;
    if (ll >= 0) acc += bf2f(zx[((size_t)b * SEQ + ll) * NPAD + DINNER + e]) * conv_w[e * 4 + wi];
  }
  xc[(size_t)bl * DXBC + e] = f2bf(siluf(acc));
}

// ---------------- dt softplus + per-chunk cumsum of dA ----------------
__global__ __launch_bounds__(128) void dt_kernel(const unsigned short* __restrict__ zx,
                                                 const float* __restrict__ dt_bias,
                                                 const float* __restrict__ A_log,
                                                 float* __restrict__ dt_soft,   // [b][h][l]
                                                 float* __restrict__ Acs,       // [b][h][c][128]
                                                 float* __restrict__ cdecay) {  // [b][h][c]
  int blk = blockIdx.x;                       // (b*64+h)*16+c
  int c = blk & 15, h = (blk >> 4) & 63, b = blk >> 10;
  int i = threadIdx.x;
  int l = c * CHUNKL + i;
  float raw = bf2f(zx[((size_t)b * SEQ + l) * NPAD + (DINNER + DXBC) + h]) + dt_bias[h];
  float dt = (raw > 20.f) ? raw : log1pf(__expf(raw));
  dt_soft[((size_t)b * 64 + h) * SEQ + l] = dt;
  float A = -__expf(A_log[h]);
  __shared__ float sbuf[128];
  sbuf[i] = dt * A;
  __syncthreads();
  for (int ofs = 1; ofs < 128; ofs <<= 1) {
    float v = (i >= ofs) ? sbuf[i - ofs] : 0.f;
    __syncthreads();
    sbuf[i] += v;
    __syncthreads();
  }
  float cs = sbuf[i];
  Acs[(((size_t)b * 64 + h) * 16 + c) * 128 + i] = cs;
  if (i == 127) cdecay[((size_t)b * 64 + h) * 16 + c] = __expf(cs);
}

// ---------------- xdt^T builder: xdtT[b][h][p][l] = x[b,l,h*64+p]*dt ----------
__global__ __launch_bounds__(256) void xdt_kernel(const unsigned short* __restrict__ xc,
                                                  const float* __restrict__ dt_soft,
                                                  unsigned short* __restrict__ xdtT) {
  int blk = blockIdx.x;                       // (b*64+h)*16+lt
  int lt = blk & 15, h = (blk >> 4) & 63, b = blk >> 10;
  __shared__ unsigned short tile[128][66];
  __shared__ float dts[128];
  int t = threadIdx.x;
  const unsigned short* xg = xc + ((size_t)b * SEQ + lt * 128) * DXBC + h * 64;
#pragma unroll
  for (int k = 0; k < 32; ++k) {
    int idx = t + k * 256;
    int row = idx >> 6, col = idx & 63;
    tile[row][col] = xg[(size_t)row * DXBC + col];
  }
  if (t < 128) dts[t] = dt_soft[((size_t)b * 64 + h) * SEQ + lt * 128 + t];
  __syncthreads();
  unsigned short* xo = xdtT + (((size_t)b * 64 + h) * 64) * SEQ + lt * 128;
#pragma unroll
  for (int k = 0; k < 32; ++k) {
    int idx = t + k * 256;
    int p = idx >> 7, j = idx & 127;
    xo[(size_t)p * SEQ + j] = f2bf(bf2f(tile[j][p]) * dts[j]);
  }
}

// ---------------- B transpose from xc: BT[b][n][l] ----------------
__global__ __launch_bounds__(256) void btr_kernel(const unsigned short* __restrict__ xc,
                                                  unsigned short* __restrict__ BT) {
  int blk = blockIdx.x;                       // b*16+lt
  int lt = blk & 15, b = blk >> 4;
  __shared__ unsigned short tile[128][129];
  int t = threadIdx.x;
  const unsigned short* src = xc + ((size_t)b * SEQ + lt * 128) * DXBC + DINNER;
#pragma unroll
  for (int k = 0; k < 64; ++k) {
    int idx = t + k * 256;
    int j = idx >> 7, n = idx & 127;
    tile[j][n] = src[(size_t)j * DXBC + n];
  }
  __syncthreads();
  unsigned short* dst = BT + (size_t)b * 128 * SEQ + lt * 128;
#pragma unroll
  for (int k = 0; k < 64; ++k) {
    int idx = t + k * 256;
    int n = idx >> 7, j = idx & 127;
    dst[(size_t)n * SEQ + j] = tile[j][n];
  }
}

// ---------------- SSD per-chunk states: states[b][c][h][p][n] ----------------
__global__ __launch_bounds__(256) void ssd_states_kernel(const unsigned short* __restrict__ BT,
                                                         const unsigned short* __restrict__ xdtT,
                                                         const float* __restrict__ Acs,
                                                         float* __restrict__ states) {
  int blk = blockIdx.x;                       // ((b*16+c)*64+h)
  int h = blk & 63, c = (blk >> 6) & 15, b = blk >> 10;
  __shared__ unsigned short BTs[128 * 128];   // [n][j]
  __shared__ unsigned short xs[64 * 128];     // [p][j]
  __shared__ float dec[128];
  int t = threadIdx.x, lane = t & 63, w = t >> 6, wr = w >> 1, wc = w & 1;
  int srow = t >> 4, scol = (t & 15) * 8;
  const unsigned short* BTb = BT + (size_t)b * 128 * SEQ + c * 128;
#pragma unroll
  for (int s = 0; s < 8; ++s) {
    int r = s * 16 + srow;
    gload16(&BTb[(size_t)r * SEQ + scol], &BTs[r * 128 + scol]);
  }
  const unsigned short* xb = xdtT + (((size_t)b * 64 + h) * 64) * SEQ + c * 128;
#pragma unroll
  for (int s = 0; s < 4; ++s) {
    int r = s * 16 + srow;
    gload16(&xb[(size_t)r * SEQ + scol], &xs[r * 128 + scol]);
  }
  const float* acsr = Acs + (((size_t)b * 64 + h) * 16 + c) * 128;
  float alast = acsr[127];
  if (t < 128) dec[t] = __expf(alast - acsr[t]);
  __syncthreads();

  f32x4_t acc[2][4];
#pragma unroll
  for (int i = 0; i < 2; ++i)
#pragma unroll
    for (int j = 0; j < 4; ++j) acc[i][j] = (f32x4_t){0.f, 0.f, 0.f, 0.f};
#pragma unroll
  for (int ks = 0; ks < 4; ++ks) {
    const int kk = ks * 32 + (lane >> 4) * 8;
    float d8[8];
#pragma unroll
    for (int e = 0; e < 8; ++e) d8[e] = dec[kk + e];
    u16x8_t af[2], bfr[4];
#pragma unroll
    for (int i = 0; i < 2; ++i) {
      u16x8_t raw = *(const u16x8_t*)&xs[(wr * 32 + i * 16 + (lane & 15)) * 128 + kk];
      u16x8_t sc;
#pragma unroll
      for (int e = 0; e < 8; ++e) sc[e] = f2bf(bf2f(raw[e]) * d8[e]);
      af[i] = sc;
    }
#pragma unroll
    for (int j = 0; j < 4; ++j)
      bfr[j] = *(const u16x8_t*)&BTs[(wc * 64 + j * 16 + (lane & 15)) * 128 + kk];
#pragma unroll
    for (int i = 0; i < 2; ++i)
#pragma unroll
      for (int j = 0; j < 4; ++j) acc[i][j] = mfma16(af[i], bfr[j], acc[i][j]);
  }
  float* so = states + ((((size_t)b * 16 + c) * 64 + h) * 64) * 128;
#pragma unroll
  for (int i = 0; i < 2; ++i) {
    int pbase = wr * 32 + i * 16 + (lane >> 4) * 4;
#pragma unroll
    for (int j = 0; j < 4; ++j) {
      int n = wc * 64 + j * 16 + (lane & 15);
#pragma unroll
      for (int r = 0; r < 4; ++r) so[(size_t)(pbase + r) * 128 + n] = acc[i][j][r];
    }
  }
}

// ---------------- inter-chunk scan (1024 blocks, 4 elem/thread) ----------------
__global__ __launch_bounds__(256) void ssd_scan_kernel(const float* __restrict__ states,
                                                       const float* __restrict__ cdecay,
                                                       unsigned short* __restrict__ prevb) {
  int blk = blockIdx.x;                       // ((b*64+h)*8 + s)
  int s = blk & 7, h = (blk >> 3) & 63, b = blk >> 9;
  int t = threadIdx.x;
  float carry[4] = {0.f, 0.f, 0.f, 0.f};
  const float* cd = cdecay + ((size_t)b * 64 + h) * 16;
  const size_t hoff = ((size_t)b * 16) * 64 + h;   // base for c stride below
  for (int c = 0; c < 16; ++c) {
    const float* sp = states + (((size_t)(b * 16 + c) * 64 + h) * 64) * 128;
    unsigned short* pp = prevb + (((size_t)(b * 16 + c) * 64 + h) * 64) * 128;
    float d = cd[c];
#pragma unroll
    for (int k = 0; k < 4; ++k) {
      int e = s * 1024 + k * 256 + t;
      pp[e] = f2bf(carry[k]);
      carry[k] = carry[k] * d + sp[e];
    }
  }
  (void)hoff;
}

// ---------------- SSD Y = Y_diag + Y_off + D*x (bf16 out) ----------------
__global__ __launch_bounds__(256) void ssd_y_kernel(const unsigned short* __restrict__ xc,
                                                    const unsigned short* __restrict__ xdtT,
                                                    const unsigned short* __restrict__ prevb,
                                                    const float* __restrict__ Acs,
                                                    const float* __restrict__ Dp,
                                                    unsigned short* __restrict__ Y) {
  int blk = blockIdx.x;                       // ((b*16+c)*64+h)
  int h = blk & 63, c = (blk >> 6) & 15, b = blk >> 10;
  __shared__ unsigned short Bs[128 * 128];    // [j][n], reused as M[i][j]
  __shared__ unsigned short Cs[128 * 128];    // [i][n]
  __shared__ unsigned short xs[64 * 128];     // [p][j]
  __shared__ unsigned short ps[64 * 128];     // [p][n]
  __shared__ float acs_s[128];
  int t = threadIdx.x, lane = t & 63, w = t >> 6, wr = w >> 1, wc = w & 1;
  int srow = t >> 4, scol = (t & 15) * 8;
  const unsigned short* Bg = xc + ((size_t)b * SEQ + c * 128) * DXBC + DINNER;
  const unsigned short* Cg = Bg + DSTATE;
#pragma unroll
  for (int s = 0; s < 8; ++s) {
    int r = s * 16 + srow;
    gload16(&Bg[(size_t)r * DXBC + scol], &Bs[r * 128 + scol]);
    gload16(&Cg[(size_t)r * DXBC + scol], &Cs[r * 128 + scol]);
  }
  const unsigned short* xg = xdtT + (((size_t)b * 64 + h) * 64) * SEQ + c * 128;
#pragma unroll
  for (int s = 0; s < 4; ++s) {
    int r = s * 16 + srow;
    gload16(&xg[(size_t)r * SEQ + scol], &xs[r * 128 + scol]);
  }
  const unsigned short* pg = prevb + ((((size_t)b * 16 + c) * 64 + h) * 64) * 128;
#pragma unroll
  for (int s = 0; s < 4; ++s) {
    int r = s * 16 + srow;
    gload16(&pg[r * 128 + scol], &ps[r * 128 + scol]);
  }
  const float* acsr = Acs + (((size_t)b * 64 + h) * 16 + c) * 128;
  if (t < 128) acs_s[t] = acsr[t];
  __syncthreads();

  // 1) CB^T: cbt -> D[m=j][n=i] = sum_n B[j,n] C[i,n]
  f32x4_t cbt[4][4];
#pragma unroll
  for (int i = 0; i < 4; ++i)
#pragma unroll
    for (int j = 0; j < 4; ++j) cbt[i][j] = (f32x4_t){0.f, 0.f, 0.f, 0.f};
#pragma unroll
  for (int ks = 0; ks < 4; ++ks) {
    const int kk = ks * 32 + (lane >> 4) * 8;
    u16x8_t af[4], bfr[4];
#pragma unroll
    for (int i = 0; i < 4; ++i) {
      af[i]  = *(const u16x8_t*)&Bs[(wr * 64 + i * 16 + (lane & 15)) * 128 + kk];
      bfr[i] = *(const u16x8_t*)&Cs[(wc * 64 + i * 16 + (lane & 15)) * 128 + kk];
    }
#pragma unroll
    for (int i = 0; i < 4; ++i)
#pragma unroll
      for (int j = 0; j < 4; ++j) cbt[i][j] = mfma16(af[i], bfr[j], cbt[i][j]);
  }
  __syncthreads();   // all waves done reading Bs before M overwrites it
  // build M[i][j] = (i>=j) ? CB * exp(acs[i]-acs[j]) : 0   (stored into Bs)
#pragma unroll
  for (int fi = 0; fi < 4; ++fi) {
#pragma unroll
    for (int fj = 0; fj < 4; ++fj) {
      int i = wc * 64 + fj * 16 + (lane & 15);
      int jb = wr * 64 + fi * 16 + (lane >> 4) * 4;
      float ai = acs_s[i];
      u16x4_t m4;
#pragma unroll
      for (int r = 0; r < 4; ++r) {
        int j = jb + r;
        float v = (i >= j) ? cbt[fi][fj][r] * __expf(ai - acs_s[j]) : 0.f;
        m4[r] = f2bf(v);
      }
      *(u16x4_t*)&Bs[i * 128 + jb] = m4;
    }
  }
  __syncthreads();

  // 2) Y_diag[i][p] = sum_j M[i,j] xdtT[p,j] ; 3) Y_off[i][p] = sum_n C[i,n] prev[p,n]
  f32x4_t accY[4][2], accO[4][2];
#pragma unroll
  for (int i = 0; i < 4; ++i)
#pragma unroll
    for (int j = 0; j < 2; ++j) {
      accY[i][j] = (f32x4_t){0.f, 0.f, 0.f, 0.f};
      accO[i][j] = (f32x4_t){0.f, 0.f, 0.f, 0.f};
    }
#pragma unroll
  for (int ks = 0; ks < 4; ++ks) {
    const int kk = ks * 32 + (lane >> 4) * 8;
    u16x8_t af[4], bfr[2], cf[4], pf[2];
#pragma unroll
    for (int i = 0; i < 4; ++i) {
      af[i] = *(const u16x8_t*)&Bs[(wr * 64 + i * 16 + (lane & 15)) * 128 + kk];
      cf[i] = *(const u16x8_t*)&Cs[(wr * 64 + i * 16 + (lane & 15)) * 128 + kk];
    }
#pragma unroll
    for (int j = 0; j < 2; ++j) {
      bfr[j] = *(const u16x8_t*)&xs[(wc * 32 + j * 16 + (lane & 15)) * 128 + kk];
      pf[j]  = *(const u16x8_t*)&ps[(wc * 32 + j * 16 + (lane & 15)) * 128 + kk];
    }
#pragma unroll
    for (int i = 0; i < 4; ++i)
#pragma unroll
      for (int j = 0; j < 2; ++j) {
        accY[i][j] = mfma16(af[i], bfr[j], accY[i][j]);
        accO[i][j] = mfma16(cf[i], pf[j], accO[i][j]);
      }
  }
  // epilogue
  float Dh = Dp[h];
  unsigned short* Yo = Y + ((size_t)b * SEQ + c * 128) * DINNER + h * 64;
  const unsigned short* xo = xc + ((size_t)b * SEQ + c * 128) * DXBC + h * 64;
#pragma unroll
  for (int fi = 0; fi < 4; ++fi) {
    int ibase = wr * 64 + fi * 16 + (lane >> 4) * 4;
#pragma unroll
    for (int r = 0; r < 4; ++r) {
      int i = ibase + r;
      float esc = __expf(acs_s[i]);
#pragma unroll
      for (int fj = 0; fj < 2; ++fj) {
        int p = wc * 32 + fj * 16 + (lane & 15);
        float v = accY[fi][fj][r] + accO[fi][fj][r] * esc + bf2f(xo[(size_t)i * DXBC + p]) * Dh;
        Yo[(size_t)i * DINNER + p] = f2bf(v);
      }
    }
  }
}

// ---------------- gated RMSNorm (bf16 Y) -> bf16 ----------------
__global__ __launch_bounds__(256) void norm_kernel(const unsigned short* __restrict__ Y,
                                                   const unsigned short* __restrict__ zx,
                                                   const float* __restrict__ nw,
                                                   unsigned short* __restrict__ yn) {
  int bl = blockIdx.x;
  const unsigned short* yr = Y + (size_t)bl * DINNER;
  const unsigned short* zr = zx + (size_t)bl * NPAD;
  int t = threadIdx.x;
  float vals[16];
  float ss = 0.f;
#pragma unroll
  for (int k = 0; k < 16; ++k) {
    int d = t + k * 256;
    float g = bf2f(yr[d]) * siluf(bf2f(zr[d]));
    vals[k] = g;
    ss += g * g;
  }
#pragma unroll
  for (int o = 32; o > 0; o >>= 1) ss += __shfl_down(ss, o, 64);
  __shared__ float red[4];
  if ((t & 63) == 0) red[t >> 6] = ss;
  __syncthreads();
  float tot = red[0] + red[1] + red[2] + red[3];
  float rs = rsqrtf(tot * (1.f / (float)DINNER) + 1e-5f);
#pragma unroll
  for (int k = 0; k < 16; ++k) {
    int d = t + k * 256;
    yn[(size_t)bl * DINNER + d] = f2bf(vals[k] * rs * nw[d]);
  }
}

// ---------------- host ----------------
extern "C" void kernel_launch(void* const* d_in, const int* in_sizes, int n_in,
                              void* d_out, int out_size, void* d_ws, size_t ws_size,
                              hipStream_t stream) {
  const float* u       = (const float*)d_in[0];
  const float* W_in    = (const float*)d_in[1];
  const float* conv_w  = (const float*)d_in[2];
  const float* conv_b  = (const float*)d_in[3];
  const float* dt_bias = (const float*)d_in[4];
  const float* A_log   = (const float*)d_in[5];
  const float* Dv      = (const float*)d_in[6];
  const float* norm_w  = (const float*)d_in[7];
  const float* W_out   = (const float*)d_in[8];
  float* out = (float*)d_out;
  (void)in_sizes; (void)n_in; (void)out_size;

  // ---- byte sizes ----
  const size_t SZ_UBF    = (size_t)BL * DMODEL * 2;
  const size_t SZ_WIN    = (size_t)NPAD * DMODEL * 2;
  const size_t SZ_XDTT   = (size_t)NBATCH * NHEADS * HEADDIM * SEQ * 2;
  const size_t SZ_ZX     = (size_t)BL * NPAD * 2;
  const size_t SZ_XC     = (size_t)BL * DXBC * 2;
  const size_t SZ_BT     = (size_t)NBATCH * DSTATE * SEQ * 2;
  const size_t SZ_DTS    = (size_t)NBATCH * NHEADS * SEQ * 4;
  const size_t SZ_ACS    = (size_t)NBATCH * NHEADS * NCHUNK * 128 * 4;
  const size_t SZ_CDEC   = (size_t)NBATCH * NHEADS * NCHUNK * 4;
  const size_t SZ_STATES = (size_t)NBATCH * NCHUNK * NHEADS * HEADDIM * DSTATE * 4; // f32; also holds Y bf16
  const size_t SZ_PREV   = (size_t)NBATCH * NCHUNK * NHEADS * HEADDIM * DSTATE * 2; // bf16; also holds yn
  const size_t REGION_A  = SZ_UBF + SZ_WIN;   // holds (u_bf,win_bf) then (xdtT,wout_bf)

  char* ws = (char*)d_ws;
  size_t off = 0;
  auto alloc = [&](size_t bytes) { char* p = ws + off; off += (bytes + 255) & ~(size_t)255; return p; };

  char* regionA = alloc(REGION_A);
  unsigned short* zx     = (unsigned short*)alloc(SZ_ZX);
  unsigned short* xc     = (unsigned short*)alloc(SZ_XC);
  unsigned short* BT     = (unsigned short*)alloc(SZ_BT);
  float* dt_soft         = (float*)alloc(SZ_DTS);
  float* Acs             = (float*)alloc(SZ_ACS);
  float* cdecay          = (float*)alloc(SZ_CDEC);
  char* statesYb         = alloc(SZ_STATES);
  char* prevYn           = alloc(SZ_PREV);
  if (off > ws_size) return;   // insufficient workspace: bail cleanly

  unsigned short* u_bf    = (unsigned short*)regionA;
  unsigned short* win_bf  = (unsigned short*)(regionA + SZ_UBF);
  unsigned short* xdtT    = (unsigned short*)regionA;
  unsigned short* wout_bf = (unsigned short*)(regionA + SZ_XDTT);
  float* states           = (float*)statesYb;
  unsigned short* Yb      = (unsigned short*)statesYb;   // bf16 Y after states dead
  unsigned short* prevb   = (unsigned short*)prevYn;
  unsigned short* yn      = (unsigned short*)prevYn;     // after prevb dead

  // phase 1 converts
  cvt_kernel<<<dim3((BL * DMODEL / 4 + 255) / 256), dim3(256), 0, stream>>>(u, u_bf, BL * DMODEL);
  cvt_win_kernel<<<dim3(NPAD * DMODEL / 4 / 256), dim3(256), 0, stream>>>(W_in, win_bf);

  // GEMM1: zx[BL][NPAD](bf16) = u_bf @ win_bf^T   (grid 1-D, swizzled)
  gemm_bt_kernel<true><<<dim3((NPAD / 128) * (BL / 128)), dim3(256), 0, stream>>>(
      u_bf, win_bf, zx, BL, NPAD, DMODEL, NPAD / 128);

  // regionA now reusable: W_out convert
  cvt_kernel<<<dim3((DMODEL * DINNER / 4 + 255) / 256), dim3(256), 0, stream>>>(W_out, wout_bf, DMODEL * DINNER);

  // conv + silu (x, B, C all inside xc)
  conv_kernel<<<dim3((int)(((size_t)BL * DXBC + 255) / 256)), dim3(256), 0, stream>>>(zx, conv_w, conv_b, xc);

  // dt softplus + cumsum
  dt_kernel<<<dim3(NBATCH * NHEADS * NCHUNK), dim3(128), 0, stream>>>(zx, dt_bias, A_log, dt_soft, Acs, cdecay);

  // xdt^T and B^T
  xdt_kernel<<<dim3(NBATCH * NHEADS * NCHUNK), dim3(256), 0, stream>>>(xc, dt_soft, xdtT);
  btr_kernel<<<dim3(NBATCH * (SEQ / 128)), dim3(256), 0, stream>>>(xc, BT);

  // SSD
  ssd_states_kernel<<<dim3(NBATCH * NCHUNK * NHEADS), dim3(256), 0, stream>>>(BT, xdtT, Acs, states);
  ssd_scan_kernel<<<dim3(NBATCH * NHEADS * 8), dim3(256), 0, stream>>>(states, cdecay, prevb);
  ssd_y_kernel<<<dim3(NBATCH * NCHUNK * NHEADS), dim3(256), 0, stream>>>(xc, xdtT, prevb, Acs, Dv, Yb);

  // gated RMSNorm (Yb bf16 -> yn; yn aliases prevb which is dead now)
  norm_kernel<<<dim3(BL), dim3(256), 0, stream>>>(Yb, zx, norm_w, yn);

  // GEMM2: out[BL][DMODEL](f32) = yn @ wout_bf^T   (grid 1-D, swizzled)
  gemm_bt_kernel<false><<<dim3((DMODEL / 128) * (BL / 128)), dim3(256), 0, stream>>>(
      yn, wout_bf, out, BL, DMODEL, DINNER, DMODEL / 128);
}

// Round 4
// 579.721 us; speedup vs baseline: 1.0946x; 1.0843x over previous
//
#include <hip/hip_runtime.h>
#include <cstdint>
#include <cstddef>

#define SEQ     2048
#define NBATCH  2
#define BL      (NBATCH*SEQ)     // 4096
#define DMODEL  2048
#define DINNER  4096
#define DSTATE  128
#define HEADDIM 64
#define NHEADS  64
#define DXBC    4352
#define DPROJ   8512
#define NPAD    8704             // padded D_IN_PROJ (34*256)
#define NCHUNK  16
#define CHUNKL  128

typedef __bf16 bf16x8_t __attribute__((ext_vector_type(8)));
typedef float f32x4_t __attribute__((ext_vector_type(4)));
typedef unsigned short u16x8_t __attribute__((ext_vector_type(8)));
typedef unsigned short u16x4_t __attribute__((ext_vector_type(4)));
typedef __attribute__((address_space(1))) unsigned int as1_u32;
typedef __attribute__((address_space(3))) unsigned int as3_u32;

__device__ __forceinline__ unsigned short f2bf(float f) {
  unsigned u = __builtin_bit_cast(unsigned, f);
  u += 0x7FFFu + ((u >> 16) & 1u);
  return (unsigned short)(u >> 16);
}
__device__ __forceinline__ float bf2f(unsigned short h) {
  unsigned u = ((unsigned)h) << 16;
  return __builtin_bit_cast(float, u);
}
__device__ __forceinline__ void gload16(const void* g, void* l) {
  __builtin_amdgcn_global_load_lds((const as1_u32*)g, (as3_u32*)l, 16, 0, 0);
}
__device__ __forceinline__ f32x4_t mfma16(u16x8_t a, u16x8_t b, f32x4_t c) {
  return __builtin_amdgcn_mfma_f32_16x16x32_bf16(
      __builtin_bit_cast(bf16x8_t, a), __builtin_bit_cast(bf16x8_t, b), c, 0, 0, 0);
}
__device__ __forceinline__ float siluf(float x) { return x / (1.f + __expf(-x)); }

// ---------------- converts ----------------
__global__ __launch_bounds__(256) void cvt_kernel(const float* __restrict__ src,
                                                  unsigned short* __restrict__ dst, int n) {
  int idx = (blockIdx.x * 256 + threadIdx.x) * 4;
  if (idx >= n) return;
  float4 v = *(const float4*)&src[idx];
  u16x4_t o; o[0] = f2bf(v.x); o[1] = f2bf(v.y); o[2] = f2bf(v.z); o[3] = f2bf(v.w);
  *(u16x4_t*)&dst[idx] = o;
}

__global__ __launch_bounds__(256) void cvt_win_kernel(const float* __restrict__ W,
                                                      unsigned short* __restrict__ dst) {
  int idx = (blockIdx.x * 256 + threadIdx.x) * 4;
  if (idx >= NPAD * DMODEL) return;
  int e = idx / DMODEL;
  u16x4_t o;
  if (e < DPROJ) {
    float4 v = *(const float4*)&W[idx];
    o[0] = f2bf(v.x); o[1] = f2bf(v.y); o[2] = f2bf(v.z); o[3] = f2bf(v.w);
  } else {
    o[0] = 0; o[1] = 0; o[2] = 0; o[3] = 0;
  }
  *(u16x4_t*)&dst[idx] = o;
}

// ---------------- GEMM 256x256, BK=32, 8 waves (2Mx4N), 4-buffer LDS ring ----
// C[M][N] = A[M][K] * B[N][K]^T, bf16 in. Counted vmcnt (T4), XOR-swizzled LDS
// (T2, derived for 64B rows: byte ^= ((row>>1)&3)<<4), setprio (T5).
// One barrier per K-tile; 4-deep buffer ring makes stage targets >=2 buffers
// away from any concurrent reader. Swizzle applied to gload SOURCE address
// (LDS dest linear) and to ds_read address — same involution (rule #21).
template <bool BF16OUT>
__global__ __launch_bounds__(512, 2) void gemm256_kernel(const unsigned short* __restrict__ A,
                                                         const unsigned short* __restrict__ B,
                                                         void* __restrict__ Cp,
                                                         int M, int N, int K, int gx) {
  __shared__ unsigned short lds[65536];   // 4 bufs x (A 16KB + B 16KB) = 128 KiB
  const int nwg = gridDim.x;
  const int q8 = nwg >> 3;
  const int lid = blockIdx.x;
  const int newid = (lid & 7) * q8 + (lid >> 3);       // bijective XCD chunking
  const int band = newid / (gx * 4);
  const int idx  = newid % (gx * 4);
  const int n0 = (idx >> 2) * 256;
  const int m0 = (band * 4 + (idx & 3)) * 256;

  const int t = threadIdx.x, lane = t & 63, w = t >> 6;
  const int wm = w >> 2, wn = w & 3;                   // 2 x 4 waves
  const int NK = K >> 5;

  f32x4_t acc[8][4];
#pragma unroll
  for (int i = 0; i < 8; ++i)
#pragma unroll
    for (int j = 0; j < 4; ++j) acc[i][j] = (f32x4_t){0.f, 0.f, 0.f, 0.f};

  // stage one 16KB unit (u even: A-tile, odd: B-tile) of K-tile u>>1
  auto stage_unit = [&](int u) {
    if (u >= 2 * NK) return;
    const int Tt = u >> 1;
    const unsigned short* G = (u & 1) ? B : A;
    const int g0 = (u & 1) ? n0 : m0;
    const int k0 = Tt << 5;
    char* base = (char*)lds + ((Tt & 3) * 32768 + (u & 1) * 16384);
#pragma unroll
    for (int i = 0; i < 2; ++i) {
      int o = i * 8192 + t * 16;
      int row = o >> 6;
      int cb = (o & 63) ^ (((row >> 1) & 3) << 4);     // inverse-swizzle source
      gload16(&G[(size_t)(g0 + row) * K + k0 + (cb >> 1)], base + o);
    }
  };

  // prologue: tiles 0,1,2 in flight (12 loads)
#pragma unroll
  for (int u = 0; u < 6; ++u) stage_unit(u);

  for (int T = 0; T < NK; ++T) {
    const int Tq = (T & 3) * 32768;
    if (T <= NK - 3)      asm volatile("s_waitcnt vmcnt(8)" ::: "memory");
    else if (T == NK - 2) asm volatile("s_waitcnt vmcnt(4)" ::: "memory");
    else                  asm volatile("s_waitcnt vmcnt(0)" ::: "memory");
    __builtin_amdgcn_s_barrier();
    asm volatile("" ::: "memory");
    __builtin_amdgcn_sched_barrier(0);

    const int kslot = (lane >> 4) * 16;                 // 16B col-slot
    u16x8_t af[8], bfr[4];
    // phase 0: read A-frags + B 0,1; stage next A-unit; MFMA nr 0,1
#pragma unroll
    for (int mr = 0; mr < 8; ++mr) {
      int row = wm * 128 + mr * 16 + (lane & 15);
      int byte = Tq + row * 64 + (kslot ^ (((row >> 1) & 3) << 4));
      af[mr] = *(const u16x8_t*)((const char*)lds + byte);
    }
#pragma unroll
    for (int nr = 0; nr < 2; ++nr) {
      int row = wn * 64 + nr * 16 + (lane & 15);
      int byte = Tq + 16384 + row * 64 + (kslot ^ (((row >> 1) & 3) << 4));
      bfr[nr] = *(const u16x8_t*)((const char*)lds + byte);
    }
    stage_unit(2 * T + 6);
    __builtin_amdgcn_s_setprio(1);
#pragma unroll
    for (int mr = 0; mr < 8; ++mr) {
      acc[mr][0] = mfma16(af[mr], bfr[0], acc[mr][0]);
      acc[mr][1] = mfma16(af[mr], bfr[1], acc[mr][1]);
    }
    __builtin_amdgcn_s_setprio(0);
    // phase 1: read B 2,3; stage next B-unit; MFMA nr 2,3
#pragma unroll
    for (int nr = 2; nr < 4; ++nr) {
      int row = wn * 64 + nr * 16 + (lane & 15);
      int byte = Tq + 16384 + row * 64 + (kslot ^ (((row >> 1) & 3) << 4));
      bfr[nr] = *(const u16x8_t*)((const char*)lds + byte);
    }
    stage_unit(2 * T + 7);
    __builtin_amdgcn_s_setprio(1);
#pragma unroll
    for (int mr = 0; mr < 8; ++mr) {
      acc[mr][2] = mfma16(af[mr], bfr[2], acc[mr][2]);
      acc[mr][3] = mfma16(af[mr], bfr[3], acc[mr][3]);
    }
    __builtin_amdgcn_s_setprio(0);
  }

  // epilogue
#pragma unroll
  for (int mr = 0; mr < 8; ++mr) {
    const int mbase = m0 + wm * 128 + mr * 16 + (lane >> 4) * 4;
#pragma unroll
    for (int nr = 0; nr < 4; ++nr) {
      const int n = n0 + wn * 64 + nr * 16 + (lane & 15);
#pragma unroll
      for (int r = 0; r < 4; ++r) {
        if (BF16OUT) ((unsigned short*)Cp)[(size_t)(mbase + r) * N + n] = f2bf(acc[mr][nr][r]);
        else         ((float*)Cp)[(size_t)(mbase + r) * N + n] = acc[mr][nr][r];
      }
    }
  }
}

// ---------------- depthwise causal conv + silu (bf16 in/out) ----------------
__global__ __launch_bounds__(256) void conv_kernel(const unsigned short* __restrict__ zx,
                                                   const float* __restrict__ conv_w,
                                                   const float* __restrict__ conv_b,
                                                   unsigned short* __restrict__ xc) {
  long long idx = (long long)blockIdx.x * 256 + threadIdx.x;
  if (idx >= (long long)BL * DXBC) return;
  int e = (int)(idx % DXBC);
  int bl = (int)(idx / DXBC);
  int l = bl % SEQ, b = bl / SEQ;
  float acc = conv_b[e];
#pragma unroll
  for (int wi = 0; wi < 4; ++wi) {
    int ll = l - 3 + wi;
    if (ll >= 0) acc += bf2f(zx[((size_t)b * SEQ + ll) * NPAD + DINNER + e]) * conv_w[e * 4 + wi];
  }
  xc[(size_t)bl * DXBC + e] = f2bf(siluf(acc));
}

// ---------------- dt softplus + per-chunk cumsum of dA ----------------
__global__ __launch_bounds__(128) void dt_kernel(const unsigned short* __restrict__ zx,
                                                 const float* __restrict__ dt_bias,
                                                 const float* __restrict__ A_log,
                                                 float* __restrict__ dt_soft,   // [b][h][l]
                                                 float* __restrict__ Acs,       // [b][h][c][128]
                                                 float* __restrict__ cdecay) {  // [b][h][c]
  int blk = blockIdx.x;                       // (b*64+h)*16+c
  int c = blk & 15, h = (blk >> 4) & 63, b = blk >> 10;
  int i = threadIdx.x;
  int l = c * CHUNKL + i;
  float raw = bf2f(zx[((size_t)b * SEQ + l) * NPAD + (DINNER + DXBC) + h]) + dt_bias[h];
  float dt = (raw > 20.f) ? raw : log1pf(__expf(raw));
  dt_soft[((size_t)b * 64 + h) * SEQ + l] = dt;
  float A = -__expf(A_log[h]);
  __shared__ float sbuf[128];
  sbuf[i] = dt * A;
  __syncthreads();
  for (int ofs = 1; ofs < 128; ofs <<= 1) {
    float v = (i >= ofs) ? sbuf[i - ofs] : 0.f;
    __syncthreads();
    sbuf[i] += v;
    __syncthreads();
  }
  float cs = sbuf[i];
  Acs[(((size_t)b * 64 + h) * 16 + c) * 128 + i] = cs;
  if (i == 127) cdecay[((size_t)b * 64 + h) * 16 + c] = __expf(cs);
}

// ---------------- xdt^T builder: xdtT[b][h][p][l] = x[b,l,h*64+p]*dt ----------
__global__ __launch_bounds__(256) void xdt_kernel(const unsigned short* __restrict__ xc,
                                                  const float* __restrict__ dt_soft,
                                                  unsigned short* __restrict__ xdtT) {
  int blk = blockIdx.x;                       // (b*64+h)*16+lt
  int lt = blk & 15, h = (blk >> 4) & 63, b = blk >> 10;
  __shared__ unsigned short tile[128][66];
  __shared__ float dts[128];
  int t = threadIdx.x;
  const unsigned short* xg = xc + ((size_t)b * SEQ + lt * 128) * DXBC + h * 64;
#pragma unroll
  for (int k = 0; k < 32; ++k) {
    int idx = t + k * 256;
    int row = idx >> 6, col = idx & 63;
    tile[row][col] = xg[(size_t)row * DXBC + col];
  }
  if (t < 128) dts[t] = dt_soft[((size_t)b * 64 + h) * SEQ + lt * 128 + t];
  __syncthreads();
  unsigned short* xo = xdtT + (((size_t)b * 64 + h) * 64) * SEQ + lt * 128;
#pragma unroll
  for (int k = 0; k < 32; ++k) {
    int idx = t + k * 256;
    int p = idx >> 7, j = idx & 127;
    xo[(size_t)p * SEQ + j] = f2bf(bf2f(tile[j][p]) * dts[j]);
  }
}

// ---------------- B transpose from xc: BT[b][n][l] ----------------
__global__ __launch_bounds__(256) void btr_kernel(const unsigned short* __restrict__ xc,
                                                  unsigned short* __restrict__ BT) {
  int blk = blockIdx.x;                       // b*16+lt
  int lt = blk & 15, b = blk >> 4;
  __shared__ unsigned short tile[128][129];
  int t = threadIdx.x;
  const unsigned short* src = xc + ((size_t)b * SEQ + lt * 128) * DXBC + DINNER;
#pragma unroll
  for (int k = 0; k < 64; ++k) {
    int idx = t + k * 256;
    int j = idx >> 7, n = idx & 127;
    tile[j][n] = src[(size_t)j * DXBC + n];
  }
  __syncthreads();
  unsigned short* dst = BT + (size_t)b * 128 * SEQ + lt * 128;
#pragma unroll
  for (int k = 0; k < 64; ++k) {
    int idx = t + k * 256;
    int n = idx >> 7, j = idx & 127;
    dst[(size_t)n * SEQ + j] = tile[j][n];
  }
}

// ---------------- SSD per-chunk states: states[b][c][h][p][n] ----------------
__global__ __launch_bounds__(256) void ssd_states_kernel(const unsigned short* __restrict__ BT,
                                                         const unsigned short* __restrict__ xdtT,
                                                         const float* __restrict__ Acs,
                                                         float* __restrict__ states) {
  int blk = blockIdx.x;                       // ((b*16+c)*64+h)
  int h = blk & 63, c = (blk >> 6) & 15, b = blk >> 10;
  __shared__ unsigned short BTs[128 * 128];   // [n][j]
  __shared__ unsigned short xs[64 * 128];     // [p][j]
  __shared__ float dec[128];
  int t = threadIdx.x, lane = t & 63, w = t >> 6, wr = w >> 1, wc = w & 1;
  int srow = t >> 4, scol = (t & 15) * 8;
  const unsigned short* BTb = BT + (size_t)b * 128 * SEQ + c * 128;
#pragma unroll
  for (int s = 0; s < 8; ++s) {
    int r = s * 16 + srow;
    gload16(&BTb[(size_t)r * SEQ + scol], &BTs[r * 128 + scol]);
  }
  const unsigned short* xb = xdtT + (((size_t)b * 64 + h) * 64) * SEQ + c * 128;
#pragma unroll
  for (int s = 0; s < 4; ++s) {
    int r = s * 16 + srow;
    gload16(&xb[(size_t)r * SEQ + scol], &xs[r * 128 + scol]);
  }
  const float* acsr = Acs + (((size_t)b * 64 + h) * 16 + c) * 128;
  float alast = acsr[127];
  if (t < 128) dec[t] = __expf(alast - acsr[t]);
  __syncthreads();

  f32x4_t acc[2][4];
#pragma unroll
  for (int i = 0; i < 2; ++i)
#pragma unroll
    for (int j = 0; j < 4; ++j) acc[i][j] = (f32x4_t){0.f, 0.f, 0.f, 0.f};
#pragma unroll
  for (int ks = 0; ks < 4; ++ks) {
    const int kk = ks * 32 + (lane >> 4) * 8;
    float d8[8];
#pragma unroll
    for (int e = 0; e < 8; ++e) d8[e] = dec[kk + e];
    u16x8_t af[2], bfr[4];
#pragma unroll
    for (int i = 0; i < 2; ++i) {
      u16x8_t raw = *(const u16x8_t*)&xs[(wr * 32 + i * 16 + (lane & 15)) * 128 + kk];
      u16x8_t sc;
#pragma unroll
      for (int e = 0; e < 8; ++e) sc[e] = f2bf(bf2f(raw[e]) * d8[e]);
      af[i] = sc;
    }
#pragma unroll
    for (int j = 0; j < 4; ++j)
      bfr[j] = *(const u16x8_t*)&BTs[(wc * 64 + j * 16 + (lane & 15)) * 128 + kk];
#pragma unroll
    for (int i = 0; i < 2; ++i)
#pragma unroll
      for (int j = 0; j < 4; ++j) acc[i][j] = mfma16(af[i], bfr[j], acc[i][j]);
  }
  float* so = states + ((((size_t)b * 16 + c) * 64 + h) * 64) * 128;
#pragma unroll
  for (int i = 0; i < 2; ++i) {
    int pbase = wr * 32 + i * 16 + (lane >> 4) * 4;
#pragma unroll
    for (int j = 0; j < 4; ++j) {
      int n = wc * 64 + j * 16 + (lane & 15);
#pragma unroll
      for (int r = 0; r < 4; ++r) so[(size_t)(pbase + r) * 128 + n] = acc[i][j][r];
    }
  }
}

// ---------------- inter-chunk scan (1024 blocks, 4 elem/thread) ----------------
__global__ __launch_bounds__(256) void ssd_scan_kernel(const float* __restrict__ states,
                                                       const float* __restrict__ cdecay,
                                                       unsigned short* __restrict__ prevb) {
  int blk = blockIdx.x;                       // ((b*64+h)*8 + s)
  int s = blk & 7, h = (blk >> 3) & 63, b = blk >> 9;
  int t = threadIdx.x;
  float carry[4] = {0.f, 0.f, 0.f, 0.f};
  const float* cd = cdecay + ((size_t)b * 64 + h) * 16;
  for (int c = 0; c < 16; ++c) {
    const float* sp = states + (((size_t)(b * 16 + c) * 64 + h) * 64) * 128;
    unsigned short* pp = prevb + (((size_t)(b * 16 + c) * 64 + h) * 64) * 128;
    float d = cd[c];
#pragma unroll
    for (int k = 0; k < 4; ++k) {
      int e = s * 1024 + k * 256 + t;
      pp[e] = f2bf(carry[k]);
      carry[k] = carry[k] * d + sp[e];
    }
  }
}

// ---------------- SSD Y = Y_diag + Y_off + D*x (bf16 out) ----------------
__global__ __launch_bounds__(256) void ssd_y_kernel(const unsigned short* __restrict__ xc,
                                                    const unsigned short* __restrict__ xdtT,
                                                    const unsigned short* __restrict__ prevb,
                                                    const float* __restrict__ Acs,
                                                    const float* __restrict__ Dp,
                                                    unsigned short* __restrict__ Y) {
  int blk = blockIdx.x;                       // ((b*16+c)*64+h)
  int h = blk & 63, c = (blk >> 6) & 15, b = blk >> 10;
  __shared__ unsigned short Bs[128 * 128];    // [j][n], reused as M[i][j]
  __shared__ unsigned short Cs[128 * 128];    // [i][n]
  __shared__ unsigned short xs[64 * 128];     // [p][j]
  __shared__ unsigned short ps[64 * 128];     // [p][n]
  __shared__ float acs_s[128];
  int t = threadIdx.x, lane = t & 63, w = t >> 6, wr = w >> 1, wc = w & 1;
  int srow = t >> 4, scol = (t & 15) * 8;
  const unsigned short* Bg = xc + ((size_t)b * SEQ + c * 128) * DXBC + DINNER;
  const unsigned short* Cg = Bg + DSTATE;
#pragma unroll
  for (int s = 0; s < 8; ++s) {
    int r = s * 16 + srow;
    gload16(&Bg[(size_t)r * DXBC + scol], &Bs[r * 128 + scol]);
    gload16(&Cg[(size_t)r * DXBC + scol], &Cs[r * 128 + scol]);
  }
  const unsigned short* xg = xdtT + (((size_t)b * 64 + h) * 64) * SEQ + c * 128;
#pragma unroll
  for (int s = 0; s < 4; ++s) {
    int r = s * 16 + srow;
    gload16(&xg[(size_t)r * SEQ + scol], &xs[r * 128 + scol]);
  }
  const unsigned short* pg = prevb + ((((size_t)b * 16 + c) * 64 + h) * 64) * 128;
#pragma unroll
  for (int s = 0; s < 4; ++s) {
    int r = s * 16 + srow;
    gload16(&pg[r * 128 + scol], &ps[r * 128 + scol]);
  }
  const float* acsr = Acs + (((size_t)b * 64 + h) * 16 + c) * 128;
  if (t < 128) acs_s[t] = acsr[t];
  __syncthreads();

  // 1) CB^T: cbt -> D[m=j][n=i] = sum_n B[j,n] C[i,n]
  f32x4_t cbt[4][4];
#pragma unroll
  for (int i = 0; i < 4; ++i)
#pragma unroll
    for (int j = 0; j < 4; ++j) cbt[i][j] = (f32x4_t){0.f, 0.f, 0.f, 0.f};
#pragma unroll
  for (int ks = 0; ks < 4; ++ks) {
    const int kk = ks * 32 + (lane >> 4) * 8;
    u16x8_t af[4], bfr[4];
#pragma unroll
    for (int i = 0; i < 4; ++i) {
      af[i]  = *(const u16x8_t*)&Bs[(wr * 64 + i * 16 + (lane & 15)) * 128 + kk];
      bfr[i] = *(const u16x8_t*)&Cs[(wc * 64 + i * 16 + (lane & 15)) * 128 + kk];
    }
#pragma unroll
    for (int i = 0; i < 4; ++i)
#pragma unroll
      for (int j = 0; j < 4; ++j) cbt[i][j] = mfma16(af[i], bfr[j], cbt[i][j]);
  }
  __syncthreads();   // all waves done reading Bs before M overwrites it
  // build M[i][j] = (i>=j) ? CB * exp(acs[i]-acs[j]) : 0   (stored into Bs)
#pragma unroll
  for (int fi = 0; fi < 4; ++fi) {
#pragma unroll
    for (int fj = 0; fj < 4; ++fj) {
      int i = wc * 64 + fj * 16 + (lane & 15);
      int jb = wr * 64 + fi * 16 + (lane >> 4) * 4;
      float ai = acs_s[i];
      u16x4_t m4;
#pragma unroll
      for (int r = 0; r < 4; ++r) {
        int j = jb + r;
        float v = (i >= j) ? cbt[fi][fj][r] * __expf(ai - acs_s[j]) : 0.f;
        m4[r] = f2bf(v);
      }
      *(u16x4_t*)&Bs[i * 128 + jb] = m4;
    }
  }
  __syncthreads();

  // 2) Y_diag[i][p] = sum_j M[i,j] xdtT[p,j] ; 3) Y_off[i][p] = sum_n C[i,n] prev[p,n]
  f32x4_t accY[4][2], accO[4][2];
#pragma unroll
  for (int i = 0; i < 4; ++i)
#pragma unroll
    for (int j = 0; j < 2; ++j) {
      accY[i][j] = (f32x4_t){0.f, 0.f, 0.f, 0.f};
      accO[i][j] = (f32x4_t){0.f, 0.f, 0.f, 0.f};
    }
#pragma unroll
  for (int ks = 0; ks < 4; ++ks) {
    const int kk = ks * 32 + (lane >> 4) * 8;
    u16x8_t af[4], bfr[2], cf[4], pf[2];
#pragma unroll
    for (int i = 0; i < 4; ++i) {
      af[i] = *(const u16x8_t*)&Bs[(wr * 64 + i * 16 + (lane & 15)) * 128 + kk];
      cf[i] = *(const u16x8_t*)&Cs[(wr * 64 + i * 16 + (lane & 15)) * 128 + kk];
    }
#pragma unroll
    for (int j = 0; j < 2; ++j) {
      bfr[j] = *(const u16x8_t*)&xs[(wc * 32 + j * 16 + (lane & 15)) * 128 + kk];
      pf[j]  = *(const u16x8_t*)&ps[(wc * 32 + j * 16 + (lane & 15)) * 128 + kk];
    }
#pragma unroll
    for (int i = 0; i < 4; ++i)
#pragma unroll
      for (int j = 0; j < 2; ++j) {
        accY[i][j] = mfma16(af[i], bfr[j], accY[i][j]);
        accO[i][j] = mfma16(cf[i], pf[j], accO[i][j]);
      }
  }
  // epilogue
  float Dh = Dp[h];
  unsigned short* Yo = Y + ((size_t)b * SEQ + c * 128) * DINNER + h * 64;
  const unsigned short* xo = xc + ((size_t)b * SEQ + c * 128) * DXBC + h * 64;
#pragma unroll
  for (int fi = 0; fi < 4; ++fi) {
    int ibase = wr * 64 + fi * 16 + (lane >> 4) * 4;
#pragma unroll
    for (int r = 0; r < 4; ++r) {
      int i = ibase + r;
      float esc = __expf(acs_s[i]);
#pragma unroll
      for (int fj = 0; fj < 2; ++fj) {
        int p = wc * 32 + fj * 16 + (lane & 15);
        float v = accY[fi][fj][r] + accO[fi][fj][r] * esc + bf2f(xo[(size_t)i * DXBC + p]) * Dh;
        Yo[(size_t)i * DINNER + p] = f2bf(v);
      }
    }
  }
}

// ---------------- gated RMSNorm (bf16 Y) -> bf16 ----------------
__global__ __launch_bounds__(256) void norm_kernel(const unsigned short* __restrict__ Y,
                                                   const unsigned short* __restrict__ zx,
                                                   const float* __restrict__ nw,
                                                   unsigned short* __restrict__ yn) {
  int bl = blockIdx.x;
  const unsigned short* yr = Y + (size_t)bl * DINNER;
  const unsigned short* zr = zx + (size_t)bl * NPAD;
  int t = threadIdx.x;
  float vals[16];
  float ss = 0.f;
#pragma unroll
  for (int k = 0; k < 16; ++k) {
    int d = t + k * 256;
    float g = bf2f(yr[d]) * siluf(bf2f(zr[d]));
    vals[k] = g;
    ss += g * g;
  }
#pragma unroll
  for (int o = 32; o > 0; o >>= 1) ss += __shfl_down(ss, o, 64);
  __shared__ float red[4];
  if ((t & 63) == 0) red[t >> 6] = ss;
  __syncthreads();
  float tot = red[0] + red[1] + red[2] + red[3];
  float rs = rsqrtf(tot * (1.f / (float)DINNER) + 1e-5f);
#pragma unroll
  for (int k = 0; k < 16; ++k) {
    int d = t + k * 256;
    yn[(size_t)bl * DINNER + d] = f2bf(vals[k] * rs * nw[d]);
  }
}

// ---------------- host ----------------
extern "C" void kernel_launch(void* const* d_in, const int* in_sizes, int n_in,
                              void* d_out, int out_size, void* d_ws, size_t ws_size,
                              hipStream_t stream) {
  const float* u       = (const float*)d_in[0];
  const float* W_in    = (const float*)d_in[1];
  const float* conv_w  = (const float*)d_in[2];
  const float* conv_b  = (const float*)d_in[3];
  const float* dt_bias = (const float*)d_in[4];
  const float* A_log   = (const float*)d_in[5];
  const float* Dv      = (const float*)d_in[6];
  const float* norm_w  = (const float*)d_in[7];
  const float* W_out   = (const float*)d_in[8];
  float* out = (float*)d_out;
  (void)in_sizes; (void)n_in; (void)out_size;

  // ---- byte sizes ----
  const size_t SZ_UBF    = (size_t)BL * DMODEL * 2;
  const size_t SZ_WIN    = (size_t)NPAD * DMODEL * 2;
  const size_t SZ_XDTT   = (size_t)NBATCH * NHEADS * HEADDIM * SEQ * 2;
  const size_t SZ_ZX     = (size_t)BL * NPAD * 2;
  const size_t SZ_XC     = (size_t)BL * DXBC * 2;
  const size_t SZ_BT     = (size_t)NBATCH * DSTATE * SEQ * 2;
  const size_t SZ_DTS    = (size_t)NBATCH * NHEADS * SEQ * 4;
  const size_t SZ_ACS    = (size_t)NBATCH * NHEADS * NCHUNK * 128 * 4;
  const size_t SZ_CDEC   = (size_t)NBATCH * NHEADS * NCHUNK * 4;
  const size_t SZ_STATES = (size_t)NBATCH * NCHUNK * NHEADS * HEADDIM * DSTATE * 4; // f32; also holds Y bf16
  const size_t SZ_PREV   = (size_t)NBATCH * NCHUNK * NHEADS * HEADDIM * DSTATE * 2; // bf16; also holds yn
  const size_t REGION_A  = SZ_UBF + SZ_WIN;   // holds (u_bf,win_bf) then (xdtT,wout_bf)

  char* ws = (char*)d_ws;
  size_t off = 0;
  auto alloc = [&](size_t bytes) { char* p = ws + off; off += (bytes + 255) & ~(size_t)255; return p; };

  char* regionA = alloc(REGION_A);
  unsigned short* zx     = (unsigned short*)alloc(SZ_ZX);
  unsigned short* xc     = (unsigned short*)alloc(SZ_XC);
  unsigned short* BT     = (unsigned short*)alloc(SZ_BT);
  float* dt_soft         = (float*)alloc(SZ_DTS);
  float* Acs             = (float*)alloc(SZ_ACS);
  float* cdecay          = (float*)alloc(SZ_CDEC);
  char* statesYb         = alloc(SZ_STATES);
  char* prevYn           = alloc(SZ_PREV);
  if (off > ws_size) return;   // insufficient workspace: bail cleanly

  unsigned short* u_bf    = (unsigned short*)regionA;
  unsigned short* win_bf  = (unsigned short*)(regionA + SZ_UBF);
  unsigned short* xdtT    = (unsigned short*)regionA;
  unsigned short* wout_bf = (unsigned short*)(regionA + SZ_XDTT);
  float* states           = (float*)statesYb;
  unsigned short* Yb      = (unsigned short*)statesYb;   // bf16 Y after states dead
  unsigned short* prevb   = (unsigned short*)prevYn;
  unsigned short* yn      = (unsigned short*)prevYn;     // after prevb dead

  // phase 1 converts
  cvt_kernel<<<dim3((BL * DMODEL / 4 + 255) / 256), dim3(256), 0, stream>>>(u, u_bf, BL * DMODEL);
  cvt_win_kernel<<<dim3(NPAD * DMODEL / 4 / 256), dim3(256), 0, stream>>>(W_in, win_bf);

  // GEMM1: zx[BL][NPAD](bf16) = u_bf @ win_bf^T   (256^2 tiles, 1-D swizzled grid)
  gemm256_kernel<true><<<dim3((NPAD / 256) * (BL / 256)), dim3(512), 0, stream>>>(
      u_bf, win_bf, zx, BL, NPAD, DMODEL, NPAD / 256);

  // regionA now reusable: W_out convert
  cvt_kernel<<<dim3((DMODEL * DINNER / 4 + 255) / 256), dim3(256), 0, stream>>>(W_out, wout_bf, DMODEL * DINNER);

  // conv + silu (x, B, C all inside xc)
  conv_kernel<<<dim3((int)(((size_t)BL * DXBC + 255) / 256)), dim3(256), 0, stream>>>(zx, conv_w, conv_b, xc);

  // dt softplus + cumsum
  dt_kernel<<<dim3(NBATCH * NHEADS * NCHUNK), dim3(128), 0, stream>>>(zx, dt_bias, A_log, dt_soft, Acs, cdecay);

  // xdt^T and B^T
  xdt_kernel<<<dim3(NBATCH * NHEADS * NCHUNK), dim3(256), 0, stream>>>(xc, dt_soft, xdtT);
  btr_kernel<<<dim3(NBATCH * (SEQ / 128)), dim3(256), 0, stream>>>(xc, BT);

  // SSD
  ssd_states_kernel<<<dim3(NBATCH * NCHUNK * NHEADS), dim3(256), 0, stream>>>(BT, xdtT, Acs, states);
  ssd_scan_kernel<<<dim3(NBATCH * NHEADS * 8), dim3(256), 0, stream>>>(states, cdecay, prevb);
  ssd_y_kernel<<<dim3(NBATCH * NCHUNK * NHEADS), dim3(256), 0, stream>>>(xc, xdtT, prevb, Acs, Dv, Yb);

  // gated RMSNorm (Yb bf16 -> yn; yn aliases prevb which is dead now)
  norm_kernel<<<dim3(BL), dim3(256), 0, stream>>>(Yb, zx, norm_w, yn);

  // GEMM2: out[BL][DMODEL](f32) = yn @ wout_bf^T   (256^2 tiles, 1-D swizzled grid)
  gemm256_kernel<false><<<dim3((DMODEL / 256) * (BL / 256)), dim3(512), 0, stream>>>(
      yn, wout_bf, out, BL, DMODEL, DINNER, DMODEL / 256);
}

// Round 5
// 568.462 us; speedup vs baseline: 1.1162x; 1.0198x over previous
//
#include <hip/hip_runtime.h>
#include <cstdint>
#include <cstddef>

#define SEQ     2048
#define NBATCH  2
#define BL      (NBATCH*SEQ)     // 4096
#define DMODEL  2048
#define DINNER  4096
#define DSTATE  128
#define HEADDIM 64
#define NHEADS  64
#define DXBC    4352
#define DPROJ   8512
#define NPAD    8704             // padded D_IN_PROJ (34*256)
#define NCHUNK  16
#define CHUNKL  128

typedef __bf16 bf16x8_t __attribute__((ext_vector_type(8)));
typedef float f32x4_t __attribute__((ext_vector_type(4)));
typedef unsigned short u16x8_t __attribute__((ext_vector_type(8)));
typedef unsigned short u16x4_t __attribute__((ext_vector_type(4)));
typedef __attribute__((address_space(1))) unsigned int as1_u32;
typedef __attribute__((address_space(3))) unsigned int as3_u32;

__device__ __forceinline__ unsigned short f2bf(float f) {
  unsigned u = __builtin_bit_cast(unsigned, f);
  u += 0x7FFFu + ((u >> 16) & 1u);
  return (unsigned short)(u >> 16);
}
__device__ __forceinline__ float bf2f(unsigned short h) {
  unsigned u = ((unsigned)h) << 16;
  return __builtin_bit_cast(float, u);
}
__device__ __forceinline__ void gload16(const void* g, void* l) {
  __builtin_amdgcn_global_load_lds((const as1_u32*)g, (as3_u32*)l, 16, 0, 0);
}
__device__ __forceinline__ f32x4_t mfma16(u16x8_t a, u16x8_t b, f32x4_t c) {
  return __builtin_amdgcn_mfma_f32_16x16x32_bf16(
      __builtin_bit_cast(bf16x8_t, a), __builtin_bit_cast(bf16x8_t, b), c, 0, 0, 0);
}
__device__ __forceinline__ float siluf(float x) { return x / (1.f + __expf(-x)); }

// ---------------- converts ----------------
__global__ __launch_bounds__(256) void cvt_kernel(const float* __restrict__ src,
                                                  unsigned short* __restrict__ dst, int n) {
  int idx = (blockIdx.x * 256 + threadIdx.x) * 4;
  if (idx >= n) return;
  float4 v = *(const float4*)&src[idx];
  u16x4_t o; o[0] = f2bf(v.x); o[1] = f2bf(v.y); o[2] = f2bf(v.z); o[3] = f2bf(v.w);
  *(u16x4_t*)&dst[idx] = o;
}

__global__ __launch_bounds__(256) void cvt_win_kernel(const float* __restrict__ W,
                                                      unsigned short* __restrict__ dst) {
  int idx = (blockIdx.x * 256 + threadIdx.x) * 4;
  if (idx >= NPAD * DMODEL) return;
  int e = idx / DMODEL;
  u16x4_t o;
  if (e < DPROJ) {
    float4 v = *(const float4*)&W[idx];
    o[0] = f2bf(v.x); o[1] = f2bf(v.y); o[2] = f2bf(v.z); o[3] = f2bf(v.w);
  } else {
    o[0] = 0; o[1] = 0; o[2] = 0; o[3] = 0;
  }
  *(u16x4_t*)&dst[idx] = o;
}

// ---------------- GEMM: C[M][N] = A[M][K] * B[N][K]^T, bf16 in ----------------
// BM = 32*WM (GEMM1: 256, GEMM2: 128), BN = 256, BK = 32. 8 waves (2M x 4N).
// 4-buffer LDS ring, counted vmcnt (T4), XOR swizzle for 64B rows (T2,
// verified 0 conflicts), fine 2-phase schedule per K-tile (T3): issue ds_reads
// + stage EARLY, barrier, lgkmcnt(0), setprio'd MFMA cluster (T5), barrier.
// One vmcnt+barrier per tile guarantees staged data visible to all waves.
template <int WM, bool BF16OUT>
__global__ __launch_bounds__(512, 2) void gemm256_kernel(const unsigned short* __restrict__ A,
                                                         const unsigned short* __restrict__ B,
                                                         void* __restrict__ Cp,
                                                         int M, int N, int K, int gx) {
  constexpr int BM  = 32 * WM;
  constexpr int AUB = BM * 64;          // A-unit bytes per K-tile
  constexpr int BUB = 16384;            // B-unit bytes (256 rows x 64B)
  constexpr int BUF = AUB + BUB;
  constexpr int LA  = AUB / 8192;       // gload instrs per thread, A unit
  constexpr int LB  = 2;
  __shared__ __attribute__((aligned(16))) char lds[4 * BUF];

  const int nwg = gridDim.x;
  const int q8 = nwg >> 3;
  const int lid = blockIdx.x;
  const int newid = (lid & 7) * q8 + (lid >> 3);     // bijective XCD chunking
  const int band = newid / (gx * 4);
  const int idx  = newid % (gx * 4);
  const int n0 = (idx >> 2) * 256;
  const int m0 = (band * 4 + (idx & 3)) * BM;

  const int t = threadIdx.x, lane = t & 63, w = t >> 6;
  const int wm = w >> 2, wn = w & 3;                 // 2 x 4 waves
  const int NK = K >> 5;
  const int kslot = (lane >> 4) * 16;                // 16B col-slot

  f32x4_t acc[WM][4];
#pragma unroll
  for (int i = 0; i < WM; ++i)
#pragma unroll
    for (int j = 0; j < 4; ++j) acc[i][j] = (f32x4_t){0.f, 0.f, 0.f, 0.f};

  auto stage_unit = [&](int u) {
    if (u >= 2 * NK) return;
    const int Tt = u >> 1;
    char* base = lds + (Tt & 3) * BUF + ((u & 1) ? AUB : 0);
    const unsigned short* G = (u & 1) ? B : A;
    const int g0 = (u & 1) ? n0 : m0;
    const int k0 = Tt << 5;
    if (u & 1) {
#pragma unroll
      for (int i = 0; i < LB; ++i) {
        int o = i * 8192 + t * 16;
        int row = o >> 6;
        int cb = (o & 63) ^ (((row >> 1) & 3) << 4);     // inverse-swizzle source
        gload16(&G[(size_t)(g0 + row) * K + k0 + (cb >> 1)], base + o);
      }
    } else {
#pragma unroll
      for (int i = 0; i < LA; ++i) {
        int o = i * 8192 + t * 16;
        int row = o >> 6;
        int cb = (o & 63) ^ (((row >> 1) & 3) << 4);
        gload16(&G[(size_t)(g0 + row) * K + k0 + (cb >> 1)], base + o);
      }
    }
  };
  auto rdA = [&](int bq, int mr) -> u16x8_t {
    int row = wm * (BM / 2) + mr * 16 + (lane & 15);
    int byte = bq * BUF + row * 64 + (kslot ^ (((row >> 1) & 3) << 4));
    return *(const u16x8_t*)(lds + byte);
  };
  auto rdB = [&](int bq, int nr) -> u16x8_t {
    int row = wn * 64 + nr * 16 + (lane & 15);
    int byte = bq * BUF + AUB + row * 64 + (kslot ^ (((row >> 1) & 3) << 4));
    return *(const u16x8_t*)(lds + byte);
  };

  // prologue: tiles 0,1,2 staged; drain tile 0 (keep 2 tiles = 2*(LA+LB) flying)
#pragma unroll
  for (int u = 0; u < 6; ++u) stage_unit(u);
  if constexpr (WM == 8) asm volatile("s_waitcnt vmcnt(8)" ::: "memory");
  else                   asm volatile("s_waitcnt vmcnt(6)" ::: "memory");
  asm volatile("" ::: "memory");
  __builtin_amdgcn_s_barrier();

  for (int T = 0; T < NK; ++T) {
    const int bq = T & 3;
    u16x8_t af[WM], bfr[4];
    // ---- phase A: issue reads early, stage, sync, MFMA cluster (nr 0,1) ----
#pragma unroll
    for (int mr = 0; mr < WM; ++mr) af[mr] = rdA(bq, mr);
    bfr[0] = rdB(bq, 0);
    bfr[1] = rdB(bq, 1);
    stage_unit(2 * T + 6);
    asm volatile("" ::: "memory");
    __builtin_amdgcn_s_barrier();
    asm volatile("s_waitcnt lgkmcnt(0)" ::: "memory");
    __builtin_amdgcn_sched_barrier(0);
    __builtin_amdgcn_s_setprio(1);
#pragma unroll
    for (int mr = 0; mr < WM; ++mr) {
      acc[mr][0] = mfma16(af[mr], bfr[0], acc[mr][0]);
      acc[mr][1] = mfma16(af[mr], bfr[1], acc[mr][1]);
    }
    __builtin_amdgcn_s_setprio(0);
    asm volatile("" ::: "memory");
    __builtin_amdgcn_s_barrier();
    // ---- phase B: reads, stage, MFMA cluster (nr 2,3), tile-boundary sync ----
    bfr[2] = rdB(bq, 2);
    bfr[3] = rdB(bq, 3);
    stage_unit(2 * T + 7);
    asm volatile("s_waitcnt lgkmcnt(0)" ::: "memory");
    __builtin_amdgcn_sched_barrier(0);
    __builtin_amdgcn_s_setprio(1);
#pragma unroll
    for (int mr = 0; mr < WM; ++mr) {
      acc[mr][2] = mfma16(af[mr], bfr[2], acc[mr][2]);
      acc[mr][3] = mfma16(af[mr], bfr[3], acc[mr][3]);
    }
    __builtin_amdgcn_s_setprio(0);
    if (T < NK - 3) {
      if constexpr (WM == 8) asm volatile("s_waitcnt vmcnt(8)" ::: "memory");
      else                   asm volatile("s_waitcnt vmcnt(6)" ::: "memory");
    } else if (T == NK - 3) {
      if constexpr (WM == 8) asm volatile("s_waitcnt vmcnt(4)" ::: "memory");
      else                   asm volatile("s_waitcnt vmcnt(3)" ::: "memory");
    } else if (T == NK - 2) {
      asm volatile("s_waitcnt vmcnt(0)" ::: "memory");
    }
    asm volatile("" ::: "memory");
    __builtin_amdgcn_s_barrier();
  }

  // epilogue
#pragma unroll
  for (int mr = 0; mr < WM; ++mr) {
    const int mbase = m0 + wm * (BM / 2) + mr * 16 + (lane >> 4) * 4;
#pragma unroll
    for (int nr = 0; nr < 4; ++nr) {
      const int n = n0 + wn * 64 + nr * 16 + (lane & 15);
#pragma unroll
      for (int r = 0; r < 4; ++r) {
        if (BF16OUT) ((unsigned short*)Cp)[(size_t)(mbase + r) * N + n] = f2bf(acc[mr][nr][r]);
        else         ((float*)Cp)[(size_t)(mbase + r) * N + n] = acc[mr][nr][r];
      }
    }
  }
}

// ---------------- depthwise causal conv + silu (bf16 in/out) ----------------
__global__ __launch_bounds__(256) void conv_kernel(const unsigned short* __restrict__ zx,
                                                   const float* __restrict__ conv_w,
                                                   const float* __restrict__ conv_b,
                                                   unsigned short* __restrict__ xc) {
  long long idx = (long long)blockIdx.x * 256 + threadIdx.x;
  if (idx >= (long long)BL * DXBC) return;
  int e = (int)(idx % DXBC);
  int bl = (int)(idx / DXBC);
  int l = bl % SEQ, b = bl / SEQ;
  float acc = conv_b[e];
#pragma unroll
  for (int wi = 0; wi < 4; ++wi) {
    int ll = l - 3 + wi;
    if (ll >= 0) acc += bf2f(zx[((size_t)b * SEQ + ll) * NPAD + DINNER + e]) * conv_w[e * 4 + wi];
  }
  xc[(size_t)bl * DXBC + e] = f2bf(siluf(acc));
}

// ---------------- dt softplus + per-chunk cumsum of dA ----------------
__global__ __launch_bounds__(128) void dt_kernel(const unsigned short* __restrict__ zx,
                                                 const float* __restrict__ dt_bias,
                                                 const float* __restrict__ A_log,
                                                 float* __restrict__ dt_soft,   // [b][h][l]
                                                 float* __restrict__ Acs,       // [b][h][c][128]
                                                 float* __restrict__ cdecay) {  // [b][h][c]
  int blk = blockIdx.x;                       // (b*64+h)*16+c
  int c = blk & 15, h = (blk >> 4) & 63, b = blk >> 10;
  int i = threadIdx.x;
  int l = c * CHUNKL + i;
  float raw = bf2f(zx[((size_t)b * SEQ + l) * NPAD + (DINNER + DXBC) + h]) + dt_bias[h];
  float dt = (raw > 20.f) ? raw : log1pf(__expf(raw));
  dt_soft[((size_t)b * 64 + h) * SEQ + l] = dt;
  float A = -__expf(A_log[h]);
  __shared__ float sbuf[128];
  sbuf[i] = dt * A;
  __syncthreads();
  for (int ofs = 1; ofs < 128; ofs <<= 1) {
    float v = (i >= ofs) ? sbuf[i - ofs] : 0.f;
    __syncthreads();
    sbuf[i] += v;
    __syncthreads();
  }
  float cs = sbuf[i];
  Acs[(((size_t)b * 64 + h) * 16 + c) * 128 + i] = cs;
  if (i == 127) cdecay[((size_t)b * 64 + h) * 16 + c] = __expf(cs);
}

// ---------------- xdt^T builder: xdtT[b][h][p][l] = x[b,l,h*64+p]*dt ----------
__global__ __launch_bounds__(256) void xdt_kernel(const unsigned short* __restrict__ xc,
                                                  const float* __restrict__ dt_soft,
                                                  unsigned short* __restrict__ xdtT) {
  int blk = blockIdx.x;                       // (b*64+h)*16+lt
  int lt = blk & 15, h = (blk >> 4) & 63, b = blk >> 10;
  __shared__ unsigned short tile[128][66];
  __shared__ float dts[128];
  int t = threadIdx.x;
  const unsigned short* xg = xc + ((size_t)b * SEQ + lt * 128) * DXBC + h * 64;
#pragma unroll
  for (int k = 0; k < 32; ++k) {
    int idx = t + k * 256;
    int row = idx >> 6, col = idx & 63;
    tile[row][col] = xg[(size_t)row * DXBC + col];
  }
  if (t < 128) dts[t] = dt_soft[((size_t)b * 64 + h) * SEQ + lt * 128 + t];
  __syncthreads();
  unsigned short* xo = xdtT + (((size_t)b * 64 + h) * 64) * SEQ + lt * 128;
#pragma unroll
  for (int k = 0; k < 32; ++k) {
    int idx = t + k * 256;
    int p = idx >> 7, j = idx & 127;
    xo[(size_t)p * SEQ + j] = f2bf(bf2f(tile[j][p]) * dts[j]);
  }
}

// ---------------- B transpose from xc: BT[b][n][l] ----------------
__global__ __launch_bounds__(256) void btr_kernel(const unsigned short* __restrict__ xc,
                                                  unsigned short* __restrict__ BT) {
  int blk = blockIdx.x;                       // b*16+lt
  int lt = blk & 15, b = blk >> 4;
  __shared__ unsigned short tile[128][129];
  int t = threadIdx.x;
  const unsigned short* src = xc + ((size_t)b * SEQ + lt * 128) * DXBC + DINNER;
#pragma unroll
  for (int k = 0; k < 64; ++k) {
    int idx = t + k * 256;
    int j = idx >> 7, n = idx & 127;
    tile[j][n] = src[(size_t)j * DXBC + n];
  }
  __syncthreads();
  unsigned short* dst = BT + (size_t)b * 128 * SEQ + lt * 128;
#pragma unroll
  for (int k = 0; k < 64; ++k) {
    int idx = t + k * 256;
    int n = idx >> 7, j = idx & 127;
    dst[(size_t)n * SEQ + j] = tile[j][n];
  }
}

// ---------------- SSD per-chunk states: states[b][c][h][p][n] ----------------
__global__ __launch_bounds__(256) void ssd_states_kernel(const unsigned short* __restrict__ BT,
                                                         const unsigned short* __restrict__ xdtT,
                                                         const float* __restrict__ Acs,
                                                         float* __restrict__ states) {
  int blk = blockIdx.x;                       // ((b*16+c)*64+h)
  int h = blk & 63, c = (blk >> 6) & 15, b = blk >> 10;
  __shared__ unsigned short BTs[128 * 128];   // [n][j]
  __shared__ unsigned short xs[64 * 128];     // [p][j]
  __shared__ float dec[128];
  int t = threadIdx.x, lane = t & 63, w = t >> 6, wr = w >> 1, wc = w & 1;
  int srow = t >> 4, scol = (t & 15) * 8;
  const unsigned short* BTb = BT + (size_t)b * 128 * SEQ + c * 128;
#pragma unroll
  for (int s = 0; s < 8; ++s) {
    int r = s * 16 + srow;
    gload16(&BTb[(size_t)r * SEQ + scol], &BTs[r * 128 + scol]);
  }
  const unsigned short* xb = xdtT + (((size_t)b * 64 + h) * 64) * SEQ + c * 128;
#pragma unroll
  for (int s = 0; s < 4; ++s) {
    int r = s * 16 + srow;
    gload16(&xb[(size_t)r * SEQ + scol], &xs[r * 128 + scol]);
  }
  const float* acsr = Acs + (((size_t)b * 64 + h) * 16 + c) * 128;
  float alast = acsr[127];
  if (t < 128) dec[t] = __expf(alast - acsr[t]);
  __syncthreads();

  f32x4_t acc[2][4];
#pragma unroll
  for (int i = 0; i < 2; ++i)
#pragma unroll
    for (int j = 0; j < 4; ++j) acc[i][j] = (f32x4_t){0.f, 0.f, 0.f, 0.f};
#pragma unroll
  for (int ks = 0; ks < 4; ++ks) {
    const int kk = ks * 32 + (lane >> 4) * 8;
    float d8[8];
#pragma unroll
    for (int e = 0; e < 8; ++e) d8[e] = dec[kk + e];
    u16x8_t af[2], bfr[4];
#pragma unroll
    for (int i = 0; i < 2; ++i) {
      u16x8_t raw = *(const u16x8_t*)&xs[(wr * 32 + i * 16 + (lane & 15)) * 128 + kk];
      u16x8_t sc;
#pragma unroll
      for (int e = 0; e < 8; ++e) sc[e] = f2bf(bf2f(raw[e]) * d8[e]);
      af[i] = sc;
    }
#pragma unroll
    for (int j = 0; j < 4; ++j)
      bfr[j] = *(const u16x8_t*)&BTs[(wc * 64 + j * 16 + (lane & 15)) * 128 + kk];
#pragma unroll
    for (int i = 0; i < 2; ++i)
#pragma unroll
      for (int j = 0; j < 4; ++j) acc[i][j] = mfma16(af[i], bfr[j], acc[i][j]);
  }
  float* so = states + ((((size_t)b * 16 + c) * 64 + h) * 64) * 128;
#pragma unroll
  for (int i = 0; i < 2; ++i) {
    int pbase = wr * 32 + i * 16 + (lane >> 4) * 4;
#pragma unroll
    for (int j = 0; j < 4; ++j) {
      int n = wc * 64 + j * 16 + (lane & 15);
#pragma unroll
      for (int r = 0; r < 4; ++r) so[(size_t)(pbase + r) * 128 + n] = acc[i][j][r];
    }
  }
}

// ---------------- inter-chunk scan (1024 blocks, 4 elem/thread) ----------------
__global__ __launch_bounds__(256) void ssd_scan_kernel(const float* __restrict__ states,
                                                       const float* __restrict__ cdecay,
                                                       unsigned short* __restrict__ prevb) {
  int blk = blockIdx.x;                       // ((b*64+h)*8 + s)
  int s = blk & 7, h = (blk >> 3) & 63, b = blk >> 9;
  int t = threadIdx.x;
  float carry[4] = {0.f, 0.f, 0.f, 0.f};
  const float* cd = cdecay + ((size_t)b * 64 + h) * 16;
  for (int c = 0; c < 16; ++c) {
    const float* sp = states + (((size_t)(b * 16 + c) * 64 + h) * 64) * 128;
    unsigned short* pp = prevb + (((size_t)(b * 16 + c) * 64 + h) * 64) * 128;
    float d = cd[c];
#pragma unroll
    for (int k = 0; k < 4; ++k) {
      int e = s * 1024 + k * 256 + t;
      pp[e] = f2bf(carry[k]);
      carry[k] = carry[k] * d + sp[e];
    }
  }
}

// ---------------- SSD Y = Y_diag + Y_off + D*x (bf16 out) ----------------
__global__ __launch_bounds__(256) void ssd_y_kernel(const unsigned short* __restrict__ xc,
                                                    const unsigned short* __restrict__ xdtT,
                                                    const unsigned short* __restrict__ prevb,
                                                    const float* __restrict__ Acs,
                                                    const float* __restrict__ Dp,
                                                    unsigned short* __restrict__ Y) {
  int blk = blockIdx.x;                       // ((b*16+c)*64+h)
  int h = blk & 63, c = (blk >> 6) & 15, b = blk >> 10;
  __shared__ unsigned short Bs[128 * 128];    // [j][n], reused as M[i][j]
  __shared__ unsigned short Cs[128 * 128];    // [i][n]
  __shared__ unsigned short xs[64 * 128];     // [p][j]
  __shared__ unsigned short ps[64 * 128];     // [p][n]
  __shared__ float acs_s[128];
  int t = threadIdx.x, lane = t & 63, w = t >> 6, wr = w >> 1, wc = w & 1;
  int srow = t >> 4, scol = (t & 15) * 8;
  const unsigned short* Bg = xc + ((size_t)b * SEQ + c * 128) * DXBC + DINNER;
  const unsigned short* Cg = Bg + DSTATE;
#pragma unroll
  for (int s = 0; s < 8; ++s) {
    int r = s * 16 + srow;
    gload16(&Bg[(size_t)r * DXBC + scol], &Bs[r * 128 + scol]);
    gload16(&Cg[(size_t)r * DXBC + scol], &Cs[r * 128 + scol]);
  }
  const unsigned short* xg = xdtT + (((size_t)b * 64 + h) * 64) * SEQ + c * 128;
#pragma unroll
  for (int s = 0; s < 4; ++s) {
    int r = s * 16 + srow;
    gload16(&xg[(size_t)r * SEQ + scol], &xs[r * 128 + scol]);
  }
  const unsigned short* pg = prevb + ((((size_t)b * 16 + c) * 64 + h) * 64) * 128;
#pragma unroll
  for (int s = 0; s < 4; ++s) {
    int r = s * 16 + srow;
    gload16(&pg[r * 128 + scol], &ps[r * 128 + scol]);
  }
  const float* acsr = Acs + (((size_t)b * 64 + h) * 16 + c) * 128;
  if (t < 128) acs_s[t] = acsr[t];
  __syncthreads();

  // 1) CB^T: cbt -> D[m=j][n=i] = sum_n B[j,n] C[i,n]
  f32x4_t cbt[4][4];
#pragma unroll
  for (int i = 0; i < 4; ++i)
#pragma unroll
    for (int j = 0; j < 4; ++j) cbt[i][j] = (f32x4_t){0.f, 0.f, 0.f, 0.f};
#pragma unroll
  for (int ks = 0; ks < 4; ++ks) {
    const int kk = ks * 32 + (lane >> 4) * 8;
    u16x8_t af[4], bfr[4];
#pragma unroll
    for (int i = 0; i < 4; ++i) {
      af[i]  = *(const u16x8_t*)&Bs[(wr * 64 + i * 16 + (lane & 15)) * 128 + kk];
      bfr[i] = *(const u16x8_t*)&Cs[(wc * 64 + i * 16 + (lane & 15)) * 128 + kk];
    }
#pragma unroll
    for (int i = 0; i < 4; ++i)
#pragma unroll
      for (int j = 0; j < 4; ++j) cbt[i][j] = mfma16(af[i], bfr[j], cbt[i][j]);
  }
  __syncthreads();   // all waves done reading Bs before M overwrites it
  // build M[i][j] = (i>=j) ? CB * exp(acs[i]-acs[j]) : 0   (stored into Bs)
#pragma unroll
  for (int fi = 0; fi < 4; ++fi) {
#pragma unroll
    for (int fj = 0; fj < 4; ++fj) {
      int i = wc * 64 + fj * 16 + (lane & 15);
      int jb = wr * 64 + fi * 16 + (lane >> 4) * 4;
      float ai = acs_s[i];
      u16x4_t m4;
#pragma unroll
      for (int r = 0; r < 4; ++r) {
        int j = jb + r;
        float v = (i >= j) ? cbt[fi][fj][r] * __expf(ai - acs_s[j]) : 0.f;
        m4[r] = f2bf(v);
      }
      *(u16x4_t*)&Bs[i * 128 + jb] = m4;
    }
  }
  __syncthreads();

  // 2) Y_diag[i][p] = sum_j M[i,j] xdtT[p,j] ; 3) Y_off[i][p] = sum_n C[i,n] prev[p,n]
  f32x4_t accY[4][2], accO[4][2];
#pragma unroll
  for (int i = 0; i < 4; ++i)
#pragma unroll
    for (int j = 0; j < 2; ++j) {
      accY[i][j] = (f32x4_t){0.f, 0.f, 0.f, 0.f};
      accO[i][j] = (f32x4_t){0.f, 0.f, 0.f, 0.f};
    }
#pragma unroll
  for (int ks = 0; ks < 4; ++ks) {
    const int kk = ks * 32 + (lane >> 4) * 8;
    u16x8_t af[4], bfr[2], cf[4], pf[2];
#pragma unroll
    for (int i = 0; i < 4; ++i) {
      af[i] = *(const u16x8_t*)&Bs[(wr * 64 + i * 16 + (lane & 15)) * 128 + kk];
      cf[i] = *(const u16x8_t*)&Cs[(wr * 64 + i * 16 + (lane & 15)) * 128 + kk];
    }
#pragma unroll
    for (int j = 0; j < 2; ++j) {
      bfr[j] = *(const u16x8_t*)&xs[(wc * 32 + j * 16 + (lane & 15)) * 128 + kk];
      pf[j]  = *(const u16x8_t*)&ps[(wc * 32 + j * 16 + (lane & 15)) * 128 + kk];
    }
#pragma unroll
    for (int i = 0; i < 4; ++i)
#pragma unroll
      for (int j = 0; j < 2; ++j) {
        accY[i][j] = mfma16(af[i], bfr[j], accY[i][j]);
        accO[i][j] = mfma16(cf[i], pf[j], accO[i][j]);
      }
  }
  // epilogue
  float Dh = Dp[h];
  unsigned short* Yo = Y + ((size_t)b * SEQ + c * 128) * DINNER + h * 64;
  const unsigned short* xo = xc + ((size_t)b * SEQ + c * 128) * DXBC + h * 64;
#pragma unroll
  for (int fi = 0; fi < 4; ++fi) {
    int ibase = wr * 64 + fi * 16 + (lane >> 4) * 4;
#pragma unroll
    for (int r = 0; r < 4; ++r) {
      int i = ibase + r;
      float esc = __expf(acs_s[i]);
#pragma unroll
      for (int fj = 0; fj < 2; ++fj) {
        int p = wc * 32 + fj * 16 + (lane & 15);
        float v = accY[fi][fj][r] + accO[fi][fj][r] * esc + bf2f(xo[(size_t)i * DXBC + p]) * Dh;
        Yo[(size_t)i * DINNER + p] = f2bf(v);
      }
    }
  }
}

// ---------------- gated RMSNorm (bf16 Y) -> bf16 ----------------
__global__ __launch_bounds__(256) void norm_kernel(const unsigned short* __restrict__ Y,
                                                   const unsigned short* __restrict__ zx,
                                                   const float* __restrict__ nw,
                                                   unsigned short* __restrict__ yn) {
  int bl = blockIdx.x;
  const unsigned short* yr = Y + (size_t)bl * DINNER;
  const unsigned short* zr = zx + (size_t)bl * NPAD;
  int t = threadIdx.x;
  float vals[16];
  float ss = 0.f;
#pragma unroll
  for (int k = 0; k < 16; ++k) {
    int d = t + k * 256;
    float g = bf2f(yr[d]) * siluf(bf2f(zr[d]));
    vals[k] = g;
    ss += g * g;
  }
#pragma unroll
  for (int o = 32; o > 0; o >>= 1) ss += __shfl_down(ss, o, 64);
  __shared__ float red[4];
  if ((t & 63) == 0) red[t >> 6] = ss;
  __syncthreads();
  float tot = red[0] + red[1] + red[2] + red[3];
  float rs = rsqrtf(tot * (1.f / (float)DINNER) + 1e-5f);
#pragma unroll
  for (int k = 0; k < 16; ++k) {
    int d = t + k * 256;
    yn[(size_t)bl * DINNER + d] = f2bf(vals[k] * rs * nw[d]);
  }
}

// ---------------- host ----------------
extern "C" void kernel_launch(void* const* d_in, const int* in_sizes, int n_in,
                              void* d_out, int out_size, void* d_ws, size_t ws_size,
                              hipStream_t stream) {
  const float* u       = (const float*)d_in[0];
  const float* W_in    = (const float*)d_in[1];
  const float* conv_w  = (const float*)d_in[2];
  const float* conv_b  = (const float*)d_in[3];
  const float* dt_bias = (const float*)d_in[4];
  const float* A_log   = (const float*)d_in[5];
  const float* Dv      = (const float*)d_in[6];
  const float* norm_w  = (const float*)d_in[7];
  const float* W_out   = (const float*)d_in[8];
  float* out = (float*)d_out;
  (void)in_sizes; (void)n_in; (void)out_size;

  // ---- byte sizes ----
  const size_t SZ_UBF    = (size_t)BL * DMODEL * 2;
  const size_t SZ_WIN    = (size_t)NPAD * DMODEL * 2;
  const size_t SZ_XDTT   = (size_t)NBATCH * NHEADS * HEADDIM * SEQ * 2;
  const size_t SZ_ZX     = (size_t)BL * NPAD * 2;
  const size_t SZ_XC     = (size_t)BL * DXBC * 2;
  const size_t SZ_BT     = (size_t)NBATCH * DSTATE * SEQ * 2;
  const size_t SZ_DTS    = (size_t)NBATCH * NHEADS * SEQ * 4;
  const size_t SZ_ACS    = (size_t)NBATCH * NHEADS * NCHUNK * 128 * 4;
  const size_t SZ_CDEC   = (size_t)NBATCH * NHEADS * NCHUNK * 4;
  const size_t SZ_STATES = (size_t)NBATCH * NCHUNK * NHEADS * HEADDIM * DSTATE * 4; // f32; also holds Y bf16
  const size_t SZ_PREV   = (size_t)NBATCH * NCHUNK * NHEADS * HEADDIM * DSTATE * 2; // bf16; also holds yn
  const size_t REGION_A  = SZ_UBF + SZ_WIN;   // holds (u_bf,win_bf) then (xdtT,wout_bf)

  char* ws = (char*)d_ws;
  size_t off = 0;
  auto alloc = [&](size_t bytes) { char* p = ws + off; off += (bytes + 255) & ~(size_t)255; return p; };

  char* regionA = alloc(REGION_A);
  unsigned short* zx     = (unsigned short*)alloc(SZ_ZX);
  unsigned short* xc     = (unsigned short*)alloc(SZ_XC);
  unsigned short* BT     = (unsigned short*)alloc(SZ_BT);
  float* dt_soft         = (float*)alloc(SZ_DTS);
  float* Acs             = (float*)alloc(SZ_ACS);
  float* cdecay          = (float*)alloc(SZ_CDEC);
  char* statesYb         = alloc(SZ_STATES);
  char* prevYn           = alloc(SZ_PREV);
  if (off > ws_size) return;   // insufficient workspace: bail cleanly

  unsigned short* u_bf    = (unsigned short*)regionA;
  unsigned short* win_bf  = (unsigned short*)(regionA + SZ_UBF);
  unsigned short* xdtT    = (unsigned short*)regionA;
  unsigned short* wout_bf = (unsigned short*)(regionA + SZ_XDTT);
  float* states           = (float*)statesYb;
  unsigned short* Yb      = (unsigned short*)statesYb;   // bf16 Y after states dead
  unsigned short* prevb   = (unsigned short*)prevYn;
  unsigned short* yn      = (unsigned short*)prevYn;     // after prevb dead

  // phase 1 converts
  cvt_kernel<<<dim3((BL * DMODEL / 4 + 255) / 256), dim3(256), 0, stream>>>(u, u_bf, BL * DMODEL);
  cvt_win_kernel<<<dim3(NPAD * DMODEL / 4 / 256), dim3(256), 0, stream>>>(W_in, win_bf);

  // GEMM1: zx[BL][NPAD](bf16) = u_bf @ win_bf^T   (BM=256, 544 blocks)
  gemm256_kernel<8, true><<<dim3((NPAD / 256) * (BL / 256)), dim3(512), 0, stream>>>(
      u_bf, win_bf, zx, BL, NPAD, DMODEL, NPAD / 256);

  // regionA now reusable: W_out convert
  cvt_kernel<<<dim3((DMODEL * DINNER / 4 + 255) / 256), dim3(256), 0, stream>>>(W_out, wout_bf, DMODEL * DINNER);

  // conv + silu (x, B, C all inside xc)
  conv_kernel<<<dim3((int)(((size_t)BL * DXBC + 255) / 256)), dim3(256), 0, stream>>>(zx, conv_w, conv_b, xc);

  // dt softplus + cumsum
  dt_kernel<<<dim3(NBATCH * NHEADS * NCHUNK), dim3(128), 0, stream>>>(zx, dt_bias, A_log, dt_soft, Acs, cdecay);

  // xdt^T and B^T
  xdt_kernel<<<dim3(NBATCH * NHEADS * NCHUNK), dim3(256), 0, stream>>>(xc, dt_soft, xdtT);
  btr_kernel<<<dim3(NBATCH * (SEQ / 128)), dim3(256), 0, stream>>>(xc, BT);

  // SSD
  ssd_states_kernel<<<dim3(NBATCH * NCHUNK * NHEADS), dim3(256), 0, stream>>>(BT, xdtT, Acs, states);
  ssd_scan_kernel<<<dim3(NBATCH * NHEADS * 8), dim3(256), 0, stream>>>(states, cdecay, prevb);
  ssd_y_kernel<<<dim3(NBATCH * NCHUNK * NHEADS), dim3(256), 0, stream>>>(xc, xdtT, prevb, Acs, Dv, Yb);

  // gated RMSNorm (Yb bf16 -> yn; yn aliases prevb which is dead now)
  norm_kernel<<<dim3(BL), dim3(256), 0, stream>>>(Yb, zx, norm_w, yn);

  // GEMM2: out[BL][DMODEL](f32) = yn @ wout_bf^T   (BM=128, 256 blocks = full device)
  gemm256_kernel<4, false><<<dim3((DMODEL / 256) * (BL / 128)), dim3(512), 0, stream>>>(
      yn, wout_bf, out, BL, DMODEL, DINNER, DMODEL / 256);
}